// Round 3
// baseline (1333.896 us; speedup 1.0000x reference)
//
#include <hip/hip_runtime.h>

#define DIM 128

// ---------------- precompute: wq[r]=w[r]@q, wk[r]=w[r]@k, c=we·e ----------------
__global__ void precompute_k(const float* __restrict__ w1, const float* __restrict__ q1,
                             const float* __restrict__ k1, const float* __restrict__ e1,
                             const float* __restrict__ we1,
                             const float* __restrict__ w2, const float* __restrict__ q2,
                             const float* __restrict__ k2, const float* __restrict__ e2,
                             const float* __restrict__ we2,
                             float* __restrict__ wqk,   // [2 layers][2 (q,k)][3][128]
                             float* __restrict__ cc)    // [2]
{
    int b = blockIdx.x;
    int i = threadIdx.x;   // 0..127
    if (b < 12) {
        int layer = b / 6;
        int rem   = b % 6;
        int which = rem / 3;   // 0=q, 1=k
        int r     = rem % 3;
        const float* w = layer ? w2 : w1;
        const float* v = layer ? (which ? k2 : q2) : (which ? k1 : q1);
        const float* row = w + (r * DIM + i) * DIM;
        float s = 0.f;
#pragma unroll 8
        for (int o = 0; o < DIM; ++o) s += row[o] * v[o];
        wqk[((layer * 2 + which) * 3 + r) * DIM + i] = s;
    } else {
        if (i < 2) {
            const float* we = i ? we2 : we1;
            const float* e  = i ? e2  : e1;
            float s = 0.f;
            for (int f = 0; f < DIM; ++f) s += we[f] * e[f];
            cc[i] = s;
        }
    }
}

// ---------------- node logits: nq3[n*3+r] = x[n]·wq[r], same for k ----------------
__global__ __launch_bounds__(256) void logits_k(const float* __restrict__ x,
    const float* __restrict__ wq, const float* __restrict__ wk,
    float* __restrict__ nq3, float* __restrict__ nk3, int N)
{
    int lane = threadIdx.x & 63;
    int n = blockIdx.x * 4 + (threadIdx.x >> 6);
    if (n >= N) return;
    float2 xv = *(const float2*)(x + (size_t)n * DIM + lane * 2);
#pragma unroll
    for (int r = 0; r < 3; ++r) {
        float2 qv = *(const float2*)(wq + r * DIM + lane * 2);
        float2 kv = *(const float2*)(wk + r * DIM + lane * 2);
        float dq = xv.x * qv.x + xv.y * qv.y;
        float dk = xv.x * kv.x + xv.y * kv.y;
#pragma unroll
        for (int off = 32; off > 0; off >>= 1) {
            dq += __shfl_xor(dq, off);
            dk += __shfl_xor(dk, off);
        }
        if (lane == 0) { nq3[n * 3 + r] = dq; nk3[n * 3 + r] = dk; }
    }
}

// ---------------- CSR build ----------------
__global__ void hist_k(const int* __restrict__ dst, int* __restrict__ hist, int E)
{
    int e = blockIdx.x * blockDim.x + threadIdx.x;
    if (e < E) atomicAdd(&hist[dst[e]], 1);
}

__global__ void scan_k(const int* __restrict__ hist, int* __restrict__ rowstart, int N)
{
    int lane = threadIdx.x;   // single wave of 64
    int running = 0;
    for (int base = 0; base < N; base += 64) {
        int i = base + lane;
        int v = (i < N) ? hist[i] : 0;
        int s = v;
#pragma unroll
        for (int off = 1; off < 64; off <<= 1) {
            int t = __shfl_up(s, off);
            if (lane >= off) s += t;
        }
        if (i < N) rowstart[i] = running + (s - v);
        running += __shfl(s, 63);
    }
    if (lane == 0) rowstart[N] = running;
}

__global__ void fill_k(const int* __restrict__ src, const int* __restrict__ dst,
                       const int* __restrict__ et, const int* __restrict__ rowstart,
                       int* __restrict__ cursor, int* __restrict__ packed,
                       int* __restrict__ eid, int E)
{
    int e = blockIdx.x * blockDim.x + threadIdx.x;
    if (e >= E) return;
    int d = dst[e];
    int pos = atomicAdd(&cursor[d], 1);
    int slot = rowstart[d] + pos;
    packed[slot] = src[e] | (et[e] << 20);
    eid[slot] = e;
}

// ---------------- per-edge: ex = exp(leaky(qi+kj+ea*c)), denom[dst] += ex ----------------
__global__ void edge_k(const int* __restrict__ src, const int* __restrict__ dst,
                       const int* __restrict__ et, const float* __restrict__ ea,
                       const float* __restrict__ nq3, const float* __restrict__ nk3,
                       const float* __restrict__ cc, int cidx,
                       float* __restrict__ exbuf, float* __restrict__ denom, int E)
{
    int e = blockIdx.x * blockDim.x + threadIdx.x;
    if (e >= E) return;
    int s = src[e], d = dst[e], t = et[e];
    float z = nq3[d * 3 + t] + nk3[s * 3 + t] + ea[e] * cc[cidx];
    float a = z > 0.f ? z : 0.2f * z;
    float ex = __expf(a);
    exbuf[e] = ex;
    atomicAdd(&denom[d], ex);
}

// ---------------- aggregation: wave per dst node, agg[n][r*128+f] ----------------
__global__ __launch_bounds__(256) void agg_k(const float* __restrict__ x,
    const int* __restrict__ packed, const int* __restrict__ eid,
    const int* __restrict__ rowstart, const float* __restrict__ exbuf,
    const float* __restrict__ denom, float* __restrict__ agg, int N)
{
    int lane = threadIdx.x & 63;
    int n = blockIdx.x * 4 + (threadIdx.x >> 6);
    if (n >= N) return;
    int s0 = rowstart[n], s1 = rowstart[n + 1];
    float inv = 1.f / (denom[n] + 1e-16f);
    float a0x = 0.f, a0y = 0.f, a1x = 0.f, a1y = 0.f, a2x = 0.f, a2y = 0.f;
    for (int sl = s0; sl < s1; ++sl) {
        int pk = packed[sl];                 // wave-uniform broadcast loads
        int e  = eid[sl];
        float attn = exbuf[e] * inv;
        int srcn = pk & 0xFFFFF;
        int t = __builtin_amdgcn_readfirstlane(pk >> 20);
        float2 xv = *(const float2*)(x + (size_t)srcn * DIM + lane * 2);
        if (t == 0)      { a0x += attn * xv.x; a0y += attn * xv.y; }
        else if (t == 1) { a1x += attn * xv.x; a1y += attn * xv.y; }
        else             { a2x += attn * xv.x; a2y += attn * xv.y; }
    }
    float* dp = agg + (size_t)n * 384 + lane * 2;
    dp[0]   = a0x; dp[1]   = a0y;
    dp[128] = a1x; dp[129] = a1y;
    dp[256] = a2x; dp[257] = a2y;
}

// ---------------- GEMM: C[M,128] = A[M,384] @ B[384,128] + bias (opt relu) ----------------
template <int RELU>
__global__ __launch_bounds__(256) void gemm_k(const float* __restrict__ A,
    const float* __restrict__ B, const float* __restrict__ bias,
    float* __restrict__ C, int M)
{
    __shared__ __align__(16) float As[128][33];
    __shared__ __align__(16) float Bs[32][132];
    int tid = threadIdx.x;
    int row0 = blockIdx.x * 128;
    int ty = tid >> 4, tx = tid & 15;
    float acc[8][8];
#pragma unroll
    for (int i = 0; i < 8; ++i)
#pragma unroll
        for (int j = 0; j < 8; ++j) acc[i][j] = 0.f;

    for (int k0 = 0; k0 < 384; k0 += 32) {
#pragma unroll
        for (int t = 0; t < 16; ++t) {
            int idx = tid + 256 * t;          // 0..4095
            int k = idx & 31, m = idx >> 5;
            int row = row0 + m;
            As[m][k] = (row < M) ? A[(size_t)row * 384 + k0 + k] : 0.f;
        }
#pragma unroll
        for (int t = 0; t < 16; ++t) {
            int idx = tid + 256 * t;
            int col = idx & 127, k = idx >> 7;
            Bs[k][col] = B[(k0 + k) * 128 + col];
        }
        __syncthreads();
#pragma unroll
        for (int k = 0; k < 32; ++k) {
            float a[8];
#pragma unroll
            for (int i = 0; i < 8; ++i) a[i] = As[ty * 8 + i][k];
            float4 b0 = *(const float4*)&Bs[k][tx * 8];
            float4 b1 = *(const float4*)&Bs[k][tx * 8 + 4];
#pragma unroll
            for (int i = 0; i < 8; ++i) {
                acc[i][0] += a[i] * b0.x; acc[i][1] += a[i] * b0.y;
                acc[i][2] += a[i] * b0.z; acc[i][3] += a[i] * b0.w;
                acc[i][4] += a[i] * b1.x; acc[i][5] += a[i] * b1.y;
                acc[i][6] += a[i] * b1.z; acc[i][7] += a[i] * b1.w;
            }
        }
        __syncthreads();
    }
#pragma unroll
    for (int i = 0; i < 8; ++i) {
        int row = row0 + ty * 8 + i;
        if (row < M) {
            float o[8];
#pragma unroll
            for (int j = 0; j < 8; ++j) {
                o[j] = acc[i][j] + bias[tx * 8 + j];
                if (RELU) o[j] = o[j] > 0.f ? o[j] : 0.f;
            }
            *(float4*)(C + (size_t)row * 128 + tx * 8)     = *(float4*)&o[0];
            *(float4*)(C + (size_t)row * 128 + tx * 8 + 4) = *(float4*)&o[4];
        }
    }
}

// ---------------- host ----------------
extern "C" void kernel_launch(void* const* d_in, const int* in_sizes, int n_in,
                              void* d_out, int out_size, void* d_ws, size_t ws_size,
                              hipStream_t stream)
{
    const float* x   = (const float*)d_in[0];
    const int*   ei  = (const int*)d_in[1];
    const int*   etp = (const int*)d_in[2];
    const float* ea  = (const float*)d_in[3];
    const float* w1  = (const float*)d_in[4];
    const float* q1  = (const float*)d_in[5];
    const float* k1  = (const float*)d_in[6];
    const float* e1  = (const float*)d_in[7];
    const float* we1 = (const float*)d_in[8];
    const float* b1  = (const float*)d_in[9];
    const float* w2  = (const float*)d_in[10];
    const float* q2  = (const float*)d_in[11];
    const float* k2  = (const float*)d_in[12];
    const float* e2  = (const float*)d_in[13];
    const float* we2 = (const float*)d_in[14];
    const float* b2  = (const float*)d_in[15];
    float* out = (float*)d_out;

    const int N = in_sizes[0] / DIM;
    const int E = in_sizes[2];
    const int* srcp = ei;
    const int* dstp = ei + E;

    char* base = (char*)d_ws;
    size_t off = 0;
    auto alloc = [&](size_t bytes) -> char* {
        char* p = base + off;
        off = (off + bytes + 255) & ~(size_t)255;
        return p;
    };
    // contiguous zero region first: hist, cursor, denom1, denom2
    int*   hist    = (int*)  alloc((size_t)N * 4);
    int*   cursor  = (int*)  alloc((size_t)N * 4);
    float* denom1  = (float*)alloc((size_t)N * 4);
    float* denom2  = (float*)alloc((size_t)N * 4);
    size_t zero_end = off;
    int*   rowstart= (int*)  alloc((size_t)(N + 1) * 4);
    float* wqk     = (float*)alloc(1536 * 4);
    float* cc      = (float*)alloc(2 * 4);
    float* nq3     = (float*)alloc((size_t)N * 3 * 4);
    float* nk3     = (float*)alloc((size_t)N * 3 * 4);
    float* exbuf   = (float*)alloc((size_t)E * 4);
    int*   packed  = (int*)  alloc((size_t)E * 4);
    int*   eid     = (int*)  alloc((size_t)E * 4);
    float* h       = (float*)alloc((size_t)N * DIM * 4);
    float* agg     = (float*)alloc((size_t)N * 384 * 4);
    (void)ws_size; (void)n_in; (void)out_size;

    hipMemsetAsync(base, 0, zero_end, stream);
    precompute_k<<<13, 128, 0, stream>>>(w1, q1, k1, e1, we1,
                                         w2, q2, k2, e2, we2, wqk, cc);
    int eb  = (E + 255) / 256;
    int nb4 = (N + 3) / 4;
    int mb  = (N + 127) / 128;

    hist_k<<<eb, 256, 0, stream>>>(dstp, hist, E);
    scan_k<<<1, 64, 0, stream>>>(hist, rowstart, N);
    fill_k<<<eb, 256, 0, stream>>>(srcp, dstp, etp, rowstart, cursor, packed, eid, E);

    // layer 1
    logits_k<<<nb4, 256, 0, stream>>>(x, wqk + 0, wqk + 384, nq3, nk3, N);
    edge_k<<<eb, 256, 0, stream>>>(srcp, dstp, etp, ea, nq3, nk3, cc, 0, exbuf, denom1, E);
    agg_k<<<nb4, 256, 0, stream>>>(x, packed, eid, rowstart, exbuf, denom1, agg, N);
    gemm_k<1><<<mb, 256, 0, stream>>>(agg, w1, b1, h, N);

    // layer 2
    logits_k<<<nb4, 256, 0, stream>>>(h, wqk + 768, wqk + 1152, nq3, nk3, N);
    edge_k<<<eb, 256, 0, stream>>>(srcp, dstp, etp, ea, nq3, nk3, cc, 1, exbuf, denom2, E);
    agg_k<<<nb4, 256, 0, stream>>>(h, packed, eid, rowstart, exbuf, denom2, agg, N);
    gemm_k<0><<<mb, 256, 0, stream>>>(agg, w2, b2, out, N);
}

// Round 5
// 863.398 us; speedup vs baseline: 1.5449x; 1.5449x over previous
//
#include <hip/hip_runtime.h>

#define DIM 128

// ---------------- precompute: wq[r]=w[r]@q, wk[r]=w[r]@k, c=we·e ----------------
__global__ void precompute_k(const float* __restrict__ w1, const float* __restrict__ q1,
                             const float* __restrict__ k1, const float* __restrict__ e1,
                             const float* __restrict__ we1,
                             const float* __restrict__ w2, const float* __restrict__ q2,
                             const float* __restrict__ k2, const float* __restrict__ e2,
                             const float* __restrict__ we2,
                             float* __restrict__ wqk,   // [2 layers][2 (q,k)][3][128]
                             float* __restrict__ cc)    // [2]
{
    int b = blockIdx.x;
    int i = threadIdx.x;   // 0..127
    if (b < 12) {
        int layer = b / 6;
        int rem   = b % 6;
        int which = rem / 3;   // 0=q, 1=k
        int r     = rem % 3;
        const float* w = layer ? w2 : w1;
        const float* v = layer ? (which ? k2 : q2) : (which ? k1 : q1);
        const float* row = w + (r * DIM + i) * DIM;
        float s = 0.f;
#pragma unroll 8
        for (int o = 0; o < DIM; ++o) s += row[o] * v[o];
        wqk[((layer * 2 + which) * 3 + r) * DIM + i] = s;
    } else {
        if (i < 2) {
            const float* we = i ? we2 : we1;
            const float* e  = i ? e2  : e1;
            float s = 0.f;
            for (int f = 0; f < DIM; ++f) s += we[f] * e[f];
            cc[i] = s;
        }
    }
}

// ---------------- node logits: nq3[n*3+r] = x[n]·wq[r], same for k ----------------
__global__ __launch_bounds__(256) void logits_k(const float* __restrict__ x,
    const float* __restrict__ wq, const float* __restrict__ wk,
    float* __restrict__ nq3, float* __restrict__ nk3, int N)
{
    int lane = threadIdx.x & 63;
    int n = blockIdx.x * 4 + (threadIdx.x >> 6);
    if (n >= N) return;
    float2 xv = *(const float2*)(x + (size_t)n * DIM + lane * 2);
#pragma unroll
    for (int r = 0; r < 3; ++r) {
        float2 qv = *(const float2*)(wq + r * DIM + lane * 2);
        float2 kv = *(const float2*)(wk + r * DIM + lane * 2);
        float dq = xv.x * qv.x + xv.y * qv.y;
        float dk = xv.x * kv.x + xv.y * kv.y;
#pragma unroll
        for (int off = 32; off > 0; off >>= 1) {
            dq += __shfl_xor(dq, off);
            dk += __shfl_xor(dk, off);
        }
        if (lane == 0) { nq3[n * 3 + r] = dq; nk3[n * 3 + r] = dk; }
    }
}

// ---------------- CSR build ----------------
__global__ void hist_k(const int* __restrict__ dst, int* __restrict__ hist, int E)
{
    int e = blockIdx.x * blockDim.x + threadIdx.x;
    if (e < E) atomicAdd(&hist[dst[e]], 1);
}

// hierarchical exclusive scan over hist[0..N): 256-element chunks
__global__ void scan1_k(const int* __restrict__ hist, int* __restrict__ bsum, int N)
{
    __shared__ int ws[4];
    int i = blockIdx.x * 256 + threadIdx.x;
    int v = (i < N) ? hist[i] : 0;
#pragma unroll
    for (int off = 32; off > 0; off >>= 1) v += __shfl_xor(v, off);
    if ((threadIdx.x & 63) == 0) ws[threadIdx.x >> 6] = v;
    __syncthreads();
    if (threadIdx.x == 0) bsum[blockIdx.x] = ws[0] + ws[1] + ws[2] + ws[3];
}

__global__ void scan2_k(const int* __restrict__ bsum, int* __restrict__ boff,
                        int* __restrict__ totalp, int nb)
{
    int lane = threadIdx.x;   // single wave
    int running = 0;
    for (int base = 0; base < nb; base += 64) {
        int i = base + lane;
        int v = (i < nb) ? bsum[i] : 0;
        int s = v;
#pragma unroll
        for (int off = 1; off < 64; off <<= 1) {
            int t = __shfl_up(s, off);
            if (lane >= off) s += t;
        }
        if (i < nb) boff[i] = running + (s - v);
        running += __shfl(s, 63);
    }
    if (lane == 0) *totalp = running;
}

__global__ void scan3_k(const int* __restrict__ hist, const int* __restrict__ boff,
                        int* __restrict__ rowstart, int N)
{
    __shared__ int ws[4];
    int tid = threadIdx.x, lane = tid & 63, w = tid >> 6;
    int i = blockIdx.x * 256 + tid;
    int v = (i < N) ? hist[i] : 0;
    int s = v;
#pragma unroll
    for (int off = 1; off < 64; off <<= 1) {
        int t = __shfl_up(s, off);
        if (lane >= off) s += t;
    }
    if (lane == 63) ws[w] = s;
    __syncthreads();
    int woff = 0;
    for (int k = 0; k < w; ++k) woff += ws[k];
    if (i < N) rowstart[i] = boff[blockIdx.x] + woff + (s - v);
}

__global__ void fill_k(const int* __restrict__ src, const int* __restrict__ dst,
                       const int* __restrict__ et, const float* __restrict__ ea,
                       const int* __restrict__ rowstart,
                       int* __restrict__ cursor, int* __restrict__ packed,
                       float* __restrict__ ea_s, int E)
{
    int e = blockIdx.x * blockDim.x + threadIdx.x;
    if (e >= E) return;
    int d = dst[e];
    int pos = atomicAdd(&cursor[d], 1);
    int slot = rowstart[d] + pos;
    packed[slot] = src[e] | (et[e] << 20);
    ea_s[slot] = ea[e];
}

// ---------------- fused softmax + aggregation: wave per dst node ----------------
// out_n = (sum_e ex_e * x[src_e]) / (sum_e ex_e + 1e-16), per relation bucket
__global__ __launch_bounds__(256) void agg_k(const float* __restrict__ x,
    const int* __restrict__ packed, const float* __restrict__ ea_s,
    const int* __restrict__ rowstart,
    const float* __restrict__ nq3, const float* __restrict__ nk3,
    const float* __restrict__ cc, int cidx,
    float* __restrict__ agg, int N)
{
    int lane = threadIdx.x & 63;
    int n = blockIdx.x * 4 + (threadIdx.x >> 6);
    if (n >= N) return;
    int s0 = rowstart[n], s1 = rowstart[n + 1];
    float c   = cc[cidx];
    float nq0 = nq3[n * 3 + 0];
    float nq1 = nq3[n * 3 + 1];
    float nq2 = nq3[n * 3 + 2];
    float den = 0.f;
    float a0x = 0.f, a0y = 0.f, a1x = 0.f, a1y = 0.f, a2x = 0.f, a2y = 0.f;
    for (int sl = s0; sl < s1; ++sl) {
        int pk    = packed[sl];      // wave-uniform
        float eav = ea_s[sl];        // wave-uniform
        int srcn  = pk & 0xFFFFF;
        int t     = __builtin_amdgcn_readfirstlane(pk >> 20);
        float nkv = nk3[srcn * 3 + t];
        float nqt = (t == 0) ? nq0 : ((t == 1) ? nq1 : nq2);
        float z   = nqt + nkv + eav * c;
        float a   = z > 0.f ? z : 0.2f * z;
        float ex  = __expf(a);
        den += ex;
        float2 xv = *(const float2*)(x + (size_t)srcn * DIM + lane * 2);
        if (t == 0)      { a0x += ex * xv.x; a0y += ex * xv.y; }
        else if (t == 1) { a1x += ex * xv.x; a1y += ex * xv.y; }
        else             { a2x += ex * xv.x; a2y += ex * xv.y; }
    }
    float inv = 1.f / (den + 1e-16f);
    float* dp = agg + (size_t)n * 384 + lane * 2;
    dp[0]   = a0x * inv; dp[1]   = a0y * inv;
    dp[128] = a1x * inv; dp[129] = a1y * inv;
    dp[256] = a2x * inv; dp[257] = a2y * inv;
}

// ---------------- GEMM: C[M,128] = A[M,384] @ B[384,128] + bias (opt relu) ----------------
template <int RELU>
__global__ __launch_bounds__(256) void gemm_k(const float* __restrict__ A,
    const float* __restrict__ B, const float* __restrict__ bias,
    float* __restrict__ C, int M)
{
    __shared__ __align__(16) float As[128][33];
    __shared__ __align__(16) float Bs[32][132];
    int tid = threadIdx.x;
    int row0 = blockIdx.x * 128;
    int ty = tid >> 4, tx = tid & 15;
    float acc[8][8];
#pragma unroll
    for (int i = 0; i < 8; ++i)
#pragma unroll
        for (int j = 0; j < 8; ++j) acc[i][j] = 0.f;

    for (int k0 = 0; k0 < 384; k0 += 32) {
#pragma unroll
        for (int t = 0; t < 16; ++t) {
            int idx = tid + 256 * t;          // 0..4095
            int k = idx & 31, m = idx >> 5;
            int row = row0 + m;
            As[m][k] = (row < M) ? A[(size_t)row * 384 + k0 + k] : 0.f;
        }
#pragma unroll
        for (int t = 0; t < 16; ++t) {
            int idx = tid + 256 * t;
            int col = idx & 127, k = idx >> 7;
            Bs[k][col] = B[(k0 + k) * 128 + col];
        }
        __syncthreads();
#pragma unroll
        for (int k = 0; k < 32; ++k) {
            float a[8];
#pragma unroll
            for (int i = 0; i < 8; ++i) a[i] = As[ty * 8 + i][k];
            float4 b0 = *(const float4*)&Bs[k][tx * 8];
            float4 b1 = *(const float4*)&Bs[k][tx * 8 + 4];
#pragma unroll
            for (int i = 0; i < 8; ++i) {
                acc[i][0] += a[i] * b0.x; acc[i][1] += a[i] * b0.y;
                acc[i][2] += a[i] * b0.z; acc[i][3] += a[i] * b0.w;
                acc[i][4] += a[i] * b1.x; acc[i][5] += a[i] * b1.y;
                acc[i][6] += a[i] * b1.z; acc[i][7] += a[i] * b1.w;
            }
        }
        __syncthreads();
    }
#pragma unroll
    for (int i = 0; i < 8; ++i) {
        int row = row0 + ty * 8 + i;
        if (row < M) {
            float o[8];
#pragma unroll
            for (int j = 0; j < 8; ++j) {
                o[j] = acc[i][j] + bias[tx * 8 + j];
                if (RELU) o[j] = o[j] > 0.f ? o[j] : 0.f;
            }
            *(float4*)(C + (size_t)row * 128 + tx * 8)     = *(float4*)&o[0];
            *(float4*)(C + (size_t)row * 128 + tx * 8 + 4) = *(float4*)&o[4];
        }
    }
}

// ---------------- host ----------------
extern "C" void kernel_launch(void* const* d_in, const int* in_sizes, int n_in,
                              void* d_out, int out_size, void* d_ws, size_t ws_size,
                              hipStream_t stream)
{
    const float* x   = (const float*)d_in[0];
    const int*   ei  = (const int*)d_in[1];
    const int*   etp = (const int*)d_in[2];
    const float* ea  = (const float*)d_in[3];
    const float* w1  = (const float*)d_in[4];
    const float* q1  = (const float*)d_in[5];
    const float* k1  = (const float*)d_in[6];
    const float* e1  = (const float*)d_in[7];
    const float* we1 = (const float*)d_in[8];
    const float* b1  = (const float*)d_in[9];
    const float* w2  = (const float*)d_in[10];
    const float* q2  = (const float*)d_in[11];
    const float* k2  = (const float*)d_in[12];
    const float* e2  = (const float*)d_in[13];
    const float* we2 = (const float*)d_in[14];
    const float* b2  = (const float*)d_in[15];
    float* out = (float*)d_out;

    const int N = in_sizes[0] / DIM;
    const int E = in_sizes[2];
    const int* srcp = ei;
    const int* dstp = ei + E;

    char* base = (char*)d_ws;
    size_t off = 0;
    auto alloc = [&](size_t bytes) -> char* {
        char* p = base + off;
        off = (off + bytes + 255) & ~(size_t)255;
        return p;
    };
    // contiguous zero region first: hist, cursor
    int*   hist    = (int*)  alloc((size_t)N * 4);
    int*   cursor  = (int*)  alloc((size_t)N * 4);
    size_t zero_end = off;
    int*   rowstart= (int*)  alloc((size_t)(N + 1) * 4);
    int*   bsum    = (int*)  alloc(256 * 4);
    int*   boff    = (int*)  alloc(256 * 4);
    float* wqk     = (float*)alloc(1536 * 4);
    float* cc      = (float*)alloc(2 * 4);
    float* nq3     = (float*)alloc((size_t)N * 3 * 4);
    float* nk3     = (float*)alloc((size_t)N * 3 * 4);
    int*   packed  = (int*)  alloc((size_t)E * 4);
    float* ea_s    = (float*)alloc((size_t)E * 4);
    float* h       = (float*)alloc((size_t)N * DIM * 4);
    float* agg     = (float*)alloc((size_t)N * 384 * 4);
    (void)ws_size; (void)n_in; (void)out_size;

    hipMemsetAsync(base, 0, zero_end, stream);
    precompute_k<<<13, 128, 0, stream>>>(w1, q1, k1, e1, we1,
                                         w2, q2, k2, e2, we2, wqk, cc);
    int eb  = (E + 255) / 256;
    int nb4 = (N + 3) / 4;
    int mb  = (N + 127) / 128;
    int sb  = (N + 255) / 256;   // scan chunks (196 for N=50000)

    hist_k<<<eb, 256, 0, stream>>>(dstp, hist, E);
    scan1_k<<<sb, 256, 0, stream>>>(hist, bsum, N);
    scan2_k<<<1, 64, 0, stream>>>(bsum, boff, rowstart + N, sb);
    scan3_k<<<sb, 256, 0, stream>>>(hist, boff, rowstart, N);
    fill_k<<<eb, 256, 0, stream>>>(srcp, dstp, etp, ea, rowstart, cursor, packed, ea_s, E);

    // layer 1
    logits_k<<<nb4, 256, 0, stream>>>(x, wqk + 0, wqk + 384, nq3, nk3, N);
    agg_k<<<nb4, 256, 0, stream>>>(x, packed, ea_s, rowstart, nq3, nk3, cc, 0, agg, N);
    gemm_k<1><<<mb, 256, 0, stream>>>(agg, w1, b1, h, N);

    // layer 2
    logits_k<<<nb4, 256, 0, stream>>>(h, wqk + 768, wqk + 1152, nq3, nk3, N);
    agg_k<<<nb4, 256, 0, stream>>>(h, packed, ea_s, rowstart, nq3, nk3, cc, 1, agg, N);
    gemm_k<0><<<mb, 256, 0, stream>>>(agg, w2, b2, out, N);
}

// Round 7
// 488.690 us; speedup vs baseline: 2.7295x; 1.7668x over previous
//
#include <hip/hip_runtime.h>

#define DIM 128

typedef __attribute__((ext_vector_type(8))) short short8;
typedef __attribute__((ext_vector_type(4))) float f32x4;

__device__ inline float bf2f(unsigned short u) {
    union { unsigned int i; float f; } v; v.i = (unsigned int)u << 16; return v.f;
}
__device__ inline unsigned short f2bf(float f) {
    union { float f; unsigned int i; } v; v.f = f;
    return (unsigned short)((v.i + 0x7FFF + ((v.i >> 16) & 1)) >> 16);
}

// ---------------- precompute: wq[r]=w[r]@q, wk[r]=w[r]@k, c=we·e (all fp32) ----------------
__global__ void precompute_k(const float* __restrict__ w1, const float* __restrict__ q1,
                             const float* __restrict__ k1, const float* __restrict__ e1,
                             const float* __restrict__ we1,
                             const float* __restrict__ w2, const float* __restrict__ q2,
                             const float* __restrict__ k2, const float* __restrict__ e2,
                             const float* __restrict__ we2,
                             float* __restrict__ wqk,   // [2][2][3][128]
                             float* __restrict__ cc)    // [2]
{
    int b = blockIdx.x;
    int i = threadIdx.x;   // 0..127
    if (b < 12) {
        int layer = b / 6;
        int rem   = b % 6;
        int which = rem / 3;
        int r     = rem % 3;
        const float* w = layer ? w2 : w1;
        const float* v = layer ? (which ? k2 : q2) : (which ? k1 : q1);
        const float* row = w + (r * DIM + i) * DIM;
        float s = 0.f;
#pragma unroll 8
        for (int o = 0; o < DIM; ++o) s += row[o] * v[o];
        wqk[((layer * 2 + which) * 3 + r) * DIM + i] = s;
    } else {
        if (i < 2) {
            const float* we = i ? we2 : we1;
            const float* e  = i ? e2  : e1;
            float s = 0.f;
            for (int f = 0; f < DIM; ++f) s += we[f] * e[f];
            cc[i] = s;
        }
    }
}

// ---------------- x fp32 -> bf16 ----------------
__global__ __launch_bounds__(256) void xconv_k(const float* __restrict__ x,
                                               unsigned short* __restrict__ xbf, int total4)
{
    int i = blockIdx.x * 256 + threadIdx.x;
    if (i >= total4) return;
    float4 v = *(const float4*)(x + (size_t)i * 4);
    unsigned short o0 = f2bf(v.x), o1 = f2bf(v.y), o2 = f2bf(v.z), o3 = f2bf(v.w);
    unsigned long long pk = (unsigned long long)o0 | ((unsigned long long)o1 << 16)
                          | ((unsigned long long)o2 << 32) | ((unsigned long long)o3 << 48);
    *(unsigned long long*)(xbf + (size_t)i * 4) = pk;
}

// ---------------- weights -> MFMA-fragment-ordered bf16 ----------------
// Bf[((layer*96 + ks*8 + f)*64 + lane)*8 + j] = bf16(w[ks*32 + (lane>>4)*8 + j][f*16 + (lane&15)])
__global__ void wconv_k(const float* __restrict__ w1, const float* __restrict__ w2,
                        unsigned short* __restrict__ Bf)
{
    int b = blockIdx.x;            // 0..191
    int lane = threadIdx.x;        // 0..63
    int layer = b / 96;
    int rem   = b % 96;
    int ks = rem / 8, f = rem % 8;
    const float* w = layer ? w2 : w1;
    int col  = f * 16 + (lane & 15);
    int krow = ks * 32 + (lane >> 4) * 8;
    unsigned short tmp[8];
#pragma unroll
    for (int j = 0; j < 8; ++j) tmp[j] = f2bf(w[(size_t)(krow + j) * 128 + col]);
    unsigned long long* dst = (unsigned long long*)(Bf + ((size_t)b * 64 + lane) * 8);
    dst[0] = *(unsigned long long*)&tmp[0];
    dst[1] = *(unsigned long long*)&tmp[4];
}

// ---------------- node logits from bf16 features ----------------
__global__ __launch_bounds__(256) void logits_k(const unsigned short* __restrict__ xbf,
    const float* __restrict__ wq, const float* __restrict__ wk,
    float* __restrict__ nq3, float* __restrict__ nk3, int N)
{
    int lane = threadIdx.x & 63;
    int n = blockIdx.x * 4 + (threadIdx.x >> 6);
    if (n >= N) return;
    unsigned int xv = *(const unsigned int*)(xbf + (size_t)n * DIM + lane * 2);
    float x0 = bf2f((unsigned short)(xv & 0xFFFF));
    float x1 = bf2f((unsigned short)(xv >> 16));
#pragma unroll
    for (int r = 0; r < 3; ++r) {
        float2 qv = *(const float2*)(wq + r * DIM + lane * 2);
        float2 kv = *(const float2*)(wk + r * DIM + lane * 2);
        float dq = x0 * qv.x + x1 * qv.y;
        float dk = x0 * kv.x + x1 * kv.y;
#pragma unroll
        for (int off = 32; off > 0; off >>= 1) {
            dq += __shfl_xor(dq, off);
            dk += __shfl_xor(dk, off);
        }
        if (lane == 0) { nq3[n * 3 + r] = dq; nk3[n * 3 + r] = dk; }
    }
}

// ---------------- CSR build ----------------
__global__ void hist_k(const int* __restrict__ dst, int* __restrict__ hist, int E)
{
    int e = blockIdx.x * blockDim.x + threadIdx.x;
    if (e < E) atomicAdd(&hist[dst[e]], 1);
}

__global__ void scan1_k(const int* __restrict__ hist, int* __restrict__ bsum, int N)
{
    __shared__ int ws[4];
    int i = blockIdx.x * 256 + threadIdx.x;
    int v = (i < N) ? hist[i] : 0;
#pragma unroll
    for (int off = 32; off > 0; off >>= 1) v += __shfl_xor(v, off);
    if ((threadIdx.x & 63) == 0) ws[threadIdx.x >> 6] = v;
    __syncthreads();
    if (threadIdx.x == 0) bsum[blockIdx.x] = ws[0] + ws[1] + ws[2] + ws[3];
}

__global__ void scan2_k(const int* __restrict__ bsum, int* __restrict__ boff,
                        int* __restrict__ totalp, int nb)
{
    int lane = threadIdx.x;
    int running = 0;
    for (int base = 0; base < nb; base += 64) {
        int i = base + lane;
        int v = (i < nb) ? bsum[i] : 0;
        int s = v;
#pragma unroll
        for (int off = 1; off < 64; off <<= 1) {
            int t = __shfl_up(s, off);
            if (lane >= off) s += t;
        }
        if (i < nb) boff[i] = running + (s - v);
        running += __shfl(s, 63);
    }
    if (lane == 0) *totalp = running;
}

__global__ void scan3_k(const int* __restrict__ hist, const int* __restrict__ boff,
                        int* __restrict__ rowstart, int N)
{
    __shared__ int ws[4];
    int tid = threadIdx.x, lane = tid & 63, w = tid >> 6;
    int i = blockIdx.x * 256 + tid;
    int v = (i < N) ? hist[i] : 0;
    int s = v;
#pragma unroll
    for (int off = 1; off < 64; off <<= 1) {
        int t = __shfl_up(s, off);
        if (lane >= off) s += t;
    }
    if (lane == 63) ws[w] = s;
    __syncthreads();
    int woff = 0;
    for (int k = 0; k < w; ++k) woff += ws[k];
    if (i < N) rowstart[i] = boff[blockIdx.x] + woff + (s - v);
}

__global__ void fill_k(const int* __restrict__ src, const int* __restrict__ dst,
                       const int* __restrict__ et, const float* __restrict__ ea,
                       const int* __restrict__ rowstart,
                       int* __restrict__ cursor, int* __restrict__ packed,
                       float* __restrict__ ea_s, int E)
{
    int e = blockIdx.x * blockDim.x + threadIdx.x;
    if (e >= E) return;
    int d = dst[e];
    int pos = atomicAdd(&cursor[d], 1);
    int slot = rowstart[d] + pos;
    packed[slot] = src[e] | (et[e] << 20);
    ea_s[slot] = ea[e];
}

// ---------------- fused softmax + aggregation (bf16 gather, bf16 out) ----------------
__global__ __launch_bounds__(256) void agg_k(const unsigned short* __restrict__ xbf,
    const int* __restrict__ packed, const float* __restrict__ ea_s,
    const int* __restrict__ rowstart,
    const float* __restrict__ nq3, const float* __restrict__ nk3,
    const float* __restrict__ cc, int cidx,
    unsigned short* __restrict__ aggbf, int N)
{
    int lane = threadIdx.x & 63;
    int n = blockIdx.x * 4 + (threadIdx.x >> 6);
    if (n >= N) return;
    int s0 = rowstart[n], s1 = rowstart[n + 1];
    float c   = cc[cidx];
    float nq0 = nq3[n * 3 + 0];
    float nq1 = nq3[n * 3 + 1];
    float nq2 = nq3[n * 3 + 2];
    float den = 0.f;
    float a0x = 0.f, a0y = 0.f, a1x = 0.f, a1y = 0.f, a2x = 0.f, a2y = 0.f;
    for (int sl = s0; sl < s1; ++sl) {
        int pk    = packed[sl];      // wave-uniform
        float eav = ea_s[sl];        // wave-uniform
        int srcn  = pk & 0xFFFFF;
        int t     = __builtin_amdgcn_readfirstlane(pk >> 20);
        float nkv = nk3[srcn * 3 + t];
        float nqt = (t == 0) ? nq0 : ((t == 1) ? nq1 : nq2);
        float z   = nqt + nkv + eav * c;
        float a   = z > 0.f ? z : 0.2f * z;
        float ex  = __expf(a);
        den += ex;
        unsigned int xv = *(const unsigned int*)(xbf + (size_t)srcn * DIM + lane * 2);
        float x0 = bf2f((unsigned short)(xv & 0xFFFF));
        float x1 = bf2f((unsigned short)(xv >> 16));
        if (t == 0)      { a0x += ex * x0; a0y += ex * x1; }
        else if (t == 1) { a1x += ex * x0; a1y += ex * x1; }
        else             { a2x += ex * x0; a2y += ex * x1; }
    }
    float inv = 1.f / (den + 1e-16f);
    unsigned short* dp = aggbf + (size_t)n * 384 + lane * 2;
    *(unsigned int*)(dp)       = (unsigned int)f2bf(a0x * inv) | ((unsigned int)f2bf(a0y * inv) << 16);
    *(unsigned int*)(dp + 128) = (unsigned int)f2bf(a1x * inv) | ((unsigned int)f2bf(a1y * inv) << 16);
    *(unsigned int*)(dp + 256) = (unsigned int)f2bf(a2x * inv) | ((unsigned int)f2bf(a2y * inv) << 16);
}

// ---------------- MFMA GEMM: C[M,128] = A[M,384]bf16 @ Bfrag + bias ----------------
// RELU=1: write bf16 h; RELU=0: write fp32 out.
template <int RELU>
__global__ __launch_bounds__(256) void gemm_mfma_k(const unsigned short* __restrict__ A,
    const unsigned short* __restrict__ Bf, const float* __restrict__ bias,
    unsigned short* __restrict__ hbf, float* __restrict__ out, int M)
{
    int wid  = threadIdx.x >> 6;
    int lane = threadIdx.x & 63;
    int mrow = blockIdx.x * 64 + wid * 16 + (lane & 15);   // row this lane LOADS for A
    int kl   = (lane >> 4) * 8;
    f32x4 acc[8];
#pragma unroll
    for (int f = 0; f < 8; ++f) acc[f] = (f32x4){0.f, 0.f, 0.f, 0.f};
    const unsigned short* arow = A + (size_t)mrow * 384 + kl;
    for (int ks = 0; ks < 12; ++ks) {
        short8 af = *(const short8*)(arow + ks * 32);
        const short8* bp = (const short8*)(Bf + ((size_t)(ks * 8) * 64 + lane) * 8);
#pragma unroll
        for (int f = 0; f < 8; ++f) {
            short8 bfr = bp[f * 64];
            acc[f] = __builtin_amdgcn_mfma_f32_16x16x32_bf16(af, bfr, acc[f], 0, 0, 0);
        }
    }
    // epilogue: D col = f*16 + (lane&15), rows = (lane>>4)*4 + j
    int r0  = blockIdx.x * 64 + wid * 16 + (lane >> 4) * 4;
    int cl  = lane & 15;
#pragma unroll
    for (int f = 0; f < 8; ++f) {
        int col = f * 16 + cl;
        float bv = bias[col];
#pragma unroll
        for (int j = 0; j < 4; ++j) {
            int row = r0 + j;
            if (row < M) {
                float v = acc[f][j] + bv;
                if (RELU) {
                    v = v > 0.f ? v : 0.f;
                    hbf[(size_t)row * 128 + col] = f2bf(v);
                } else {
                    out[(size_t)row * 128 + col] = v;
                }
            }
        }
    }
}

// ---------------- host ----------------
extern "C" void kernel_launch(void* const* d_in, const int* in_sizes, int n_in,
                              void* d_out, int out_size, void* d_ws, size_t ws_size,
                              hipStream_t stream)
{
    const float* x   = (const float*)d_in[0];
    const int*   ei  = (const int*)d_in[1];
    const int*   etp = (const int*)d_in[2];
    const float* ea  = (const float*)d_in[3];
    const float* w1  = (const float*)d_in[4];
    const float* q1  = (const float*)d_in[5];
    const float* k1  = (const float*)d_in[6];
    const float* e1  = (const float*)d_in[7];
    const float* we1 = (const float*)d_in[8];
    const float* b1  = (const float*)d_in[9];
    const float* w2  = (const float*)d_in[10];
    const float* q2  = (const float*)d_in[11];
    const float* k2  = (const float*)d_in[12];
    const float* e2  = (const float*)d_in[13];
    const float* we2 = (const float*)d_in[14];
    const float* b2  = (const float*)d_in[15];
    float* out = (float*)d_out;

    const int N = in_sizes[0] / DIM;
    const int E = in_sizes[2];
    const int* srcp = ei;
    const int* dstp = ei + E;

    int mb64 = (N + 63) / 64;          // MFMA gemm blocks
    int Mpad = mb64 * 64;              // padded rows for unguarded A-frag loads

    char* base = (char*)d_ws;
    size_t off = 0;
    auto alloc = [&](size_t bytes) -> char* {
        char* p = base + off;
        off = (off + bytes + 255) & ~(size_t)255;
        return p;
    };
    int*   hist    = (int*)  alloc((size_t)N * 4);
    int*   cursor  = (int*)  alloc((size_t)N * 4);
    size_t zero_end = off;
    int*   rowstart= (int*)  alloc((size_t)(N + 1) * 4);
    int*   bsum    = (int*)  alloc(256 * 4);
    int*   boff    = (int*)  alloc(256 * 4);
    float* wqk     = (float*)alloc(1536 * 4);
    float* cc      = (float*)alloc(2 * 4);
    float* nq3     = (float*)alloc((size_t)N * 3 * 4);
    float* nk3     = (float*)alloc((size_t)N * 3 * 4);
    int*   packed  = (int*)  alloc((size_t)E * 4);
    float* ea_s    = (float*)alloc((size_t)E * 4);
    unsigned short* xbf   = (unsigned short*)alloc((size_t)N * DIM * 2);
    unsigned short* hbf   = (unsigned short*)alloc((size_t)N * DIM * 2);
    unsigned short* aggbf = (unsigned short*)alloc((size_t)Mpad * 384 * 2);
    unsigned short* Bf    = (unsigned short*)alloc((size_t)2 * 96 * 64 * 8 * 2);
    (void)ws_size; (void)n_in; (void)out_size;

    hipMemsetAsync(base, 0, zero_end, stream);
    precompute_k<<<13, 128, 0, stream>>>(w1, q1, k1, e1, we1,
                                         w2, q2, k2, e2, we2, wqk, cc);
    int eb  = (E + 255) / 256;
    int nb4 = (N + 3) / 4;
    int sb  = (N + 255) / 256;
    int total4 = N * DIM / 4;

    xconv_k<<<(total4 + 255) / 256, 256, 0, stream>>>(x, xbf, total4);
    wconv_k<<<192, 64, 0, stream>>>(w1, w2, Bf);

    hist_k<<<eb, 256, 0, stream>>>(dstp, hist, E);
    scan1_k<<<sb, 256, 0, stream>>>(hist, bsum, N);
    scan2_k<<<1, 64, 0, stream>>>(bsum, boff, rowstart + N, sb);
    scan3_k<<<sb, 256, 0, stream>>>(hist, boff, rowstart, N);
    fill_k<<<eb, 256, 0, stream>>>(srcp, dstp, etp, ea, rowstart, cursor, packed, ea_s, E);

    const unsigned short* Bf2 = Bf + (size_t)96 * 64 * 8;

    // layer 1
    logits_k<<<nb4, 256, 0, stream>>>(xbf, wqk + 0, wqk + 384, nq3, nk3, N);
    agg_k<<<nb4, 256, 0, stream>>>(xbf, packed, ea_s, rowstart, nq3, nk3, cc, 0, aggbf, N);
    gemm_mfma_k<1><<<mb64, 256, 0, stream>>>(aggbf, Bf, b1, hbf, nullptr, N);

    // layer 2
    logits_k<<<nb4, 256, 0, stream>>>(hbf, wqk + 768, wqk + 1152, nq3, nk3, N);
    agg_k<<<nb4, 256, 0, stream>>>(hbf, packed, ea_s, rowstart, nq3, nk3, cc, 1, aggbf, N);
    gemm_mfma_k<0><<<mb64, 256, 0, stream>>>(aggbf, Bf2, b2, nullptr, out, N);
}

// Round 8
// 469.303 us; speedup vs baseline: 2.8423x; 1.0413x over previous
//
#include <hip/hip_runtime.h>

#define DIM 128

typedef __attribute__((ext_vector_type(8))) short short8;
typedef __attribute__((ext_vector_type(4))) float f32x4;

__device__ inline float bf2f(unsigned short u) {
    union { unsigned int i; float f; } v; v.i = (unsigned int)u << 16; return v.f;
}
__device__ inline unsigned short f2bf(float f) {
    union { float f; unsigned int i; } v; v.f = f;
    return (unsigned short)((v.i + 0x7FFF + ((v.i >> 16) & 1)) >> 16);
}

// ---------------- precompute: wq[r]=w[r]@q, wk[r]=w[r]@k, c=we·e (all fp32) ----------------
__global__ void precompute_k(const float* __restrict__ w1, const float* __restrict__ q1,
                             const float* __restrict__ k1, const float* __restrict__ e1,
                             const float* __restrict__ we1,
                             const float* __restrict__ w2, const float* __restrict__ q2,
                             const float* __restrict__ k2, const float* __restrict__ e2,
                             const float* __restrict__ we2,
                             float* __restrict__ wqk,   // [2][2][3][128]
                             float* __restrict__ cc)    // [2]
{
    int b = blockIdx.x;
    int i = threadIdx.x;   // 0..127
    if (b < 12) {
        int layer = b / 6;
        int rem   = b % 6;
        int which = rem / 3;
        int r     = rem % 3;
        const float* w = layer ? w2 : w1;
        const float* v = layer ? (which ? k2 : q2) : (which ? k1 : q1);
        const float* row = w + (r * DIM + i) * DIM;
        float s = 0.f;
#pragma unroll 8
        for (int o = 0; o < DIM; ++o) s += row[o] * v[o];
        wqk[((layer * 2 + which) * 3 + r) * DIM + i] = s;
    } else {
        if (i < 2) {
            const float* we = i ? we2 : we1;
            const float* e  = i ? e2  : e1;
            float s = 0.f;
            for (int f = 0; f < DIM; ++f) s += we[f] * e[f];
            cc[i] = s;
        }
    }
}

// ---------------- x fp32 -> bf16 ----------------
__global__ __launch_bounds__(256) void xconv_k(const float* __restrict__ x,
                                               unsigned short* __restrict__ xbf, int total4)
{
    int i = blockIdx.x * 256 + threadIdx.x;
    if (i >= total4) return;
    float4 v = *(const float4*)(x + (size_t)i * 4);
    unsigned short o0 = f2bf(v.x), o1 = f2bf(v.y), o2 = f2bf(v.z), o3 = f2bf(v.w);
    unsigned long long pk = (unsigned long long)o0 | ((unsigned long long)o1 << 16)
                          | ((unsigned long long)o2 << 32) | ((unsigned long long)o3 << 48);
    *(unsigned long long*)(xbf + (size_t)i * 4) = pk;
}

// ---------------- weights -> MFMA-fragment-ordered bf16 ----------------
__global__ void wconv_k(const float* __restrict__ w1, const float* __restrict__ w2,
                        unsigned short* __restrict__ Bf)
{
    int b = blockIdx.x;            // 0..191
    int lane = threadIdx.x;        // 0..63
    int layer = b / 96;
    int rem   = b % 96;
    int ks = rem / 8, f = rem % 8;
    const float* w = layer ? w2 : w1;
    int col  = f * 16 + (lane & 15);
    int krow = ks * 32 + (lane >> 4) * 8;
    unsigned short tmp[8];
#pragma unroll
    for (int j = 0; j < 8; ++j) tmp[j] = f2bf(w[(size_t)(krow + j) * 128 + col]);
    unsigned long long* dst = (unsigned long long*)(Bf + ((size_t)b * 64 + lane) * 8);
    dst[0] = *(unsigned long long*)&tmp[0];
    dst[1] = *(unsigned long long*)&tmp[4];
}

// ---------------- node logits from bf16 features ----------------
__global__ __launch_bounds__(256) void logits_k(const unsigned short* __restrict__ xbf,
    const float* __restrict__ wq, const float* __restrict__ wk,
    float* __restrict__ nq3, float* __restrict__ nk3, int N)
{
    int lane = threadIdx.x & 63;
    int n = blockIdx.x * 4 + (threadIdx.x >> 6);
    if (n >= N) return;
    unsigned int xv = *(const unsigned int*)(xbf + (size_t)n * DIM + lane * 2);
    float x0 = bf2f((unsigned short)(xv & 0xFFFF));
    float x1 = bf2f((unsigned short)(xv >> 16));
#pragma unroll
    for (int r = 0; r < 3; ++r) {
        float2 qv = *(const float2*)(wq + r * DIM + lane * 2);
        float2 kv = *(const float2*)(wk + r * DIM + lane * 2);
        float dq = x0 * qv.x + x1 * qv.y;
        float dk = x0 * kv.x + x1 * kv.y;
#pragma unroll
        for (int off = 32; off > 0; off >>= 1) {
            dq += __shfl_xor(dq, off);
            dk += __shfl_xor(dk, off);
        }
        if (lane == 0) { nq3[n * 3 + r] = dq; nk3[n * 3 + r] = dk; }
    }
}

// ---------------- CSR build over (dst,rel) buckets: 3N entries ----------------
__global__ void hist_k(const int* __restrict__ dst, const int* __restrict__ et,
                       int* __restrict__ hist3, int E)
{
    int e = blockIdx.x * blockDim.x + threadIdx.x;
    if (e < E) atomicAdd(&hist3[dst[e] * 3 + et[e]], 1);
}

__global__ void scan1_k(const int* __restrict__ hist, int* __restrict__ bsum, int N)
{
    __shared__ int ws[4];
    int i = blockIdx.x * 256 + threadIdx.x;
    int v = (i < N) ? hist[i] : 0;
#pragma unroll
    for (int off = 32; off > 0; off >>= 1) v += __shfl_xor(v, off);
    if ((threadIdx.x & 63) == 0) ws[threadIdx.x >> 6] = v;
    __syncthreads();
    if (threadIdx.x == 0) bsum[blockIdx.x] = ws[0] + ws[1] + ws[2] + ws[3];
}

__global__ void scan2_k(const int* __restrict__ bsum, int* __restrict__ boff,
                        int* __restrict__ totalp, int nb)
{
    int lane = threadIdx.x;
    int running = 0;
    for (int base = 0; base < nb; base += 64) {
        int i = base + lane;
        int v = (i < nb) ? bsum[i] : 0;
        int s = v;
#pragma unroll
        for (int off = 1; off < 64; off <<= 1) {
            int t = __shfl_up(s, off);
            if (lane >= off) s += t;
        }
        if (i < nb) boff[i] = running + (s - v);
        running += __shfl(s, 63);
    }
    if (lane == 0) *totalp = running;
}

__global__ void scan3_k(const int* __restrict__ hist, const int* __restrict__ boff,
                        int* __restrict__ rowstart, int N)
{
    __shared__ int ws[4];
    int tid = threadIdx.x, lane = tid & 63, w = tid >> 6;
    int i = blockIdx.x * 256 + tid;
    int v = (i < N) ? hist[i] : 0;
    int s = v;
#pragma unroll
    for (int off = 1; off < 64; off <<= 1) {
        int t = __shfl_up(s, off);
        if (lane >= off) s += t;
    }
    if (lane == 63) ws[w] = s;
    __syncthreads();
    int woff = 0;
    for (int k = 0; k < w; ++k) woff += ws[k];
    if (i < N) rowstart[i] = boff[blockIdx.x] + woff + (s - v);
}

__global__ void fill_k(const int* __restrict__ src, const int* __restrict__ dst,
                       const int* __restrict__ et, const float* __restrict__ ea,
                       const int* __restrict__ rowstart3,
                       int* __restrict__ cursor3, int* __restrict__ packed,
                       float* __restrict__ ea_s, int* __restrict__ dst_s, int E)
{
    int e = blockIdx.x * blockDim.x + threadIdx.x;
    if (e >= E) return;
    int d = dst[e], t = et[e];
    int b3 = d * 3 + t;
    int pos = atomicAdd(&cursor3[b3], 1);
    int slot = rowstart3[b3] + pos;
    packed[slot] = src[e];
    ea_s[slot] = ea[e];
    dst_s[slot] = d;
}

// ---------------- per-slot softmax numerator: ex_s[sl] (slot-ordered, rel from segment) ----------------
__global__ __launch_bounds__(256) void edgeex_k(const int* __restrict__ packed,
    const float* __restrict__ ea_s, const int* __restrict__ dst_s,
    const int* __restrict__ rowstart3,
    const float* __restrict__ nq3, const float* __restrict__ nk3,
    const float* __restrict__ cc, int cidx,
    float* __restrict__ ex_s, int E)
{
    int sl = blockIdx.x * 256 + threadIdx.x;
    if (sl >= E) return;
    int srcn = packed[sl];
    int d    = dst_s[sl];
    // recover relation: which of the 3 segments of row d contains sl
    int b3 = d * 3;
    int t = (sl >= rowstart3[b3 + 1]) + (sl >= rowstart3[b3 + 2]);
    float z = nq3[b3 + t] + nk3[srcn * 3 + t] + ea_s[sl] * cc[cidx];
    float a = z > 0.f ? z : 0.2f * z;
    ex_s[sl] = __expf(a);
}

// ---------------- aggregation: wave per dst node, 3 contiguous relation segments ----------------
__global__ __launch_bounds__(256) void agg_k(const unsigned short* __restrict__ xbf,
    const int* __restrict__ packed, const float* __restrict__ ex_s,
    const int* __restrict__ rowstart3,
    unsigned short* __restrict__ aggbf, int N)
{
    int lane = threadIdx.x & 63;
    int n = blockIdx.x * 4 + (threadIdx.x >> 6);
    if (n >= N) return;
    int b3 = n * 3;
    int rs[4];
#pragma unroll
    for (int r = 0; r < 4; ++r) rs[r] = rowstart3[b3 + r];
    float den = 0.f;
    float ax0 = 0.f, ay0 = 0.f, ax1 = 0.f, ay1 = 0.f, ax2 = 0.f, ay2 = 0.f;
#pragma unroll
    for (int r = 0; r < 3; ++r) {
        float axl = 0.f, ayl = 0.f;
        for (int sl = rs[r]; sl < rs[r + 1]; ++sl) {
            float ex  = ex_s[sl];        // wave-uniform broadcast
            int  srcn = packed[sl];      // wave-uniform broadcast
            unsigned int xv = *(const unsigned int*)(xbf + (size_t)srcn * DIM + lane * 2);
            float x0 = bf2f((unsigned short)(xv & 0xFFFF));
            float x1 = bf2f((unsigned short)(xv >> 16));
            axl += ex * x0;
            ayl += ex * x1;
            den += ex;
        }
        if (r == 0)      { ax0 = axl; ay0 = ayl; }
        else if (r == 1) { ax1 = axl; ay1 = ayl; }
        else             { ax2 = axl; ay2 = ayl; }
    }
    float inv = 1.f / (den + 1e-16f);
    unsigned short* dp = aggbf + (size_t)n * 384 + lane * 2;
    *(unsigned int*)(dp)       = (unsigned int)f2bf(ax0 * inv) | ((unsigned int)f2bf(ay0 * inv) << 16);
    *(unsigned int*)(dp + 128) = (unsigned int)f2bf(ax1 * inv) | ((unsigned int)f2bf(ay1 * inv) << 16);
    *(unsigned int*)(dp + 256) = (unsigned int)f2bf(ax2 * inv) | ((unsigned int)f2bf(ay2 * inv) << 16);
}

// ---------------- MFMA GEMM: C[M,128] = A[M,384]bf16 @ Bfrag + bias ----------------
template <int RELU>
__global__ __launch_bounds__(256) void gemm_mfma_k(const unsigned short* __restrict__ A,
    const unsigned short* __restrict__ Bf, const float* __restrict__ bias,
    unsigned short* __restrict__ hbf, float* __restrict__ out, int M)
{
    int wid  = threadIdx.x >> 6;
    int lane = threadIdx.x & 63;
    int mrow = blockIdx.x * 64 + wid * 16 + (lane & 15);
    int kl   = (lane >> 4) * 8;
    f32x4 acc[8];
#pragma unroll
    for (int f = 0; f < 8; ++f) acc[f] = (f32x4){0.f, 0.f, 0.f, 0.f};
    const unsigned short* arow = A + (size_t)mrow * 384 + kl;
    for (int ks = 0; ks < 12; ++ks) {
        short8 af = *(const short8*)(arow + ks * 32);
        const short8* bp = (const short8*)(Bf + ((size_t)(ks * 8) * 64 + lane) * 8);
#pragma unroll
        for (int f = 0; f < 8; ++f) {
            short8 bfr = bp[f * 64];
            acc[f] = __builtin_amdgcn_mfma_f32_16x16x32_bf16(af, bfr, acc[f], 0, 0, 0);
        }
    }
    int r0  = blockIdx.x * 64 + wid * 16 + (lane >> 4) * 4;
    int cl  = lane & 15;
#pragma unroll
    for (int f = 0; f < 8; ++f) {
        int col = f * 16 + cl;
        float bv = bias[col];
#pragma unroll
        for (int j = 0; j < 4; ++j) {
            int row = r0 + j;
            if (row < M) {
                float v = acc[f][j] + bv;
                if (RELU) {
                    v = v > 0.f ? v : 0.f;
                    hbf[(size_t)row * 128 + col] = f2bf(v);
                } else {
                    out[(size_t)row * 128 + col] = v;
                }
            }
        }
    }
}

// ---------------- host ----------------
extern "C" void kernel_launch(void* const* d_in, const int* in_sizes, int n_in,
                              void* d_out, int out_size, void* d_ws, size_t ws_size,
                              hipStream_t stream)
{
    const float* x   = (const float*)d_in[0];
    const int*   ei  = (const int*)d_in[1];
    const int*   etp = (const int*)d_in[2];
    const float* ea  = (const float*)d_in[3];
    const float* w1  = (const float*)d_in[4];
    const float* q1  = (const float*)d_in[5];
    const float* k1  = (const float*)d_in[6];
    const float* e1  = (const float*)d_in[7];
    const float* we1 = (const float*)d_in[8];
    const float* b1  = (const float*)d_in[9];
    const float* w2  = (const float*)d_in[10];
    const float* q2  = (const float*)d_in[11];
    const float* k2  = (const float*)d_in[12];
    const float* e2  = (const float*)d_in[13];
    const float* we2 = (const float*)d_in[14];
    const float* b2  = (const float*)d_in[15];
    float* out = (float*)d_out;

    const int N = in_sizes[0] / DIM;
    const int E = in_sizes[2];
    const int N3 = N * 3;
    const int* srcp = ei;
    const int* dstp = ei + E;

    int mb64 = (N + 63) / 64;
    int Mpad = mb64 * 64;

    char* base = (char*)d_ws;
    size_t off = 0;
    auto alloc = [&](size_t bytes) -> char* {
        char* p = base + off;
        off = (off + bytes + 255) & ~(size_t)255;
        return p;
    };
    int*   hist3   = (int*)  alloc((size_t)N3 * 4);
    int*   cursor3 = (int*)  alloc((size_t)N3 * 4);
    size_t zero_end = off;
    int*   rowstart3 = (int*)alloc((size_t)(N3 + 1) * 4);
    int*   bsum    = (int*)  alloc(1024 * 4);
    int*   boff    = (int*)  alloc(1024 * 4);
    float* wqk     = (float*)alloc(1536 * 4);
    float* cc      = (float*)alloc(2 * 4);
    float* nq3     = (float*)alloc((size_t)N * 3 * 4);
    float* nk3     = (float*)alloc((size_t)N * 3 * 4);
    int*   packed  = (int*)  alloc((size_t)E * 4);
    float* ea_s    = (float*)alloc((size_t)E * 4);
    int*   dst_s   = (int*)  alloc((size_t)E * 4);
    float* ex_s    = (float*)alloc((size_t)E * 4);
    unsigned short* xbf   = (unsigned short*)alloc((size_t)N * DIM * 2);
    unsigned short* hbf   = (unsigned short*)alloc((size_t)N * DIM * 2);
    unsigned short* aggbf = (unsigned short*)alloc((size_t)Mpad * 384 * 2);
    unsigned short* Bf    = (unsigned short*)alloc((size_t)2 * 96 * 64 * 8 * 2);
    (void)ws_size; (void)n_in; (void)out_size;

    hipMemsetAsync(base, 0, zero_end, stream);
    precompute_k<<<13, 128, 0, stream>>>(w1, q1, k1, e1, we1,
                                         w2, q2, k2, e2, we2, wqk, cc);
    int eb  = (E + 255) / 256;
    int nb4 = (N + 3) / 4;
    int sb3 = (N3 + 255) / 256;
    int total4 = N * DIM / 4;

    xconv_k<<<(total4 + 255) / 256, 256, 0, stream>>>(x, xbf, total4);
    wconv_k<<<192, 64, 0, stream>>>(w1, w2, Bf);

    hist_k<<<eb, 256, 0, stream>>>(dstp, etp, hist3, E);
    scan1_k<<<sb3, 256, 0, stream>>>(hist3, bsum, N3);
    scan2_k<<<1, 64, 0, stream>>>(bsum, boff, rowstart3 + N3, sb3);
    scan3_k<<<sb3, 256, 0, stream>>>(hist3, boff, rowstart3, N3);
    fill_k<<<eb, 256, 0, stream>>>(srcp, dstp, etp, ea, rowstart3, cursor3,
                                   packed, ea_s, dst_s, E);

    const unsigned short* Bf2 = Bf + (size_t)96 * 64 * 8;

    // layer 1
    logits_k<<<nb4, 256, 0, stream>>>(xbf, wqk + 0, wqk + 384, nq3, nk3, N);
    edgeex_k<<<eb, 256, 0, stream>>>(packed, ea_s, dst_s, rowstart3, nq3, nk3, cc, 0, ex_s, E);
    agg_k<<<nb4, 256, 0, stream>>>(xbf, packed, ex_s, rowstart3, aggbf, N);
    gemm_mfma_k<1><<<mb64, 256, 0, stream>>>(aggbf, Bf, b1, hbf, nullptr, N);

    // layer 2
    logits_k<<<nb4, 256, 0, stream>>>(hbf, wqk + 768, wqk + 1152, nq3, nk3, N);
    edgeex_k<<<eb, 256, 0, stream>>>(packed, ea_s, dst_s, rowstart3, nq3, nk3, cc, 1, ex_s, E);
    agg_k<<<nb4, 256, 0, stream>>>(hbf, packed, ex_s, rowstart3, aggbf, N);
    gemm_mfma_k<0><<<mb64, 256, 0, stream>>>(aggbf, Bf2, b2, nullptr, out, N);
}

// Round 12
// 413.042 us; speedup vs baseline: 3.2294x; 1.1362x over previous
//
#include <hip/hip_runtime.h>

#define DIM 128

typedef __attribute__((ext_vector_type(8))) short short8;
typedef __attribute__((ext_vector_type(4))) float f32x4;

__device__ inline float bf2f(unsigned short u) {
    union { unsigned int i; float f; } v; v.i = (unsigned int)u << 16; return v.f;
}
__device__ inline unsigned short f2bf(float f) {
    union { float f; unsigned int i; } v; v.f = f;
    return (unsigned short)((v.i + 0x7FFF + ((v.i >> 16) & 1)) >> 16);
}

// ---------------- precompute: wq[r]=w[r]@q, wk[r]=w[r]@k, c=we·e (all fp32) ----------------
__global__ void precompute_k(const float* __restrict__ w1, const float* __restrict__ q1,
                             const float* __restrict__ k1, const float* __restrict__ e1,
                             const float* __restrict__ we1,
                             const float* __restrict__ w2, const float* __restrict__ q2,
                             const float* __restrict__ k2, const float* __restrict__ e2,
                             const float* __restrict__ we2,
                             float* __restrict__ wqk,   // [2][2][3][128]
                             float* __restrict__ cc)    // [2]
{
    int b = blockIdx.x;
    int i = threadIdx.x;   // 0..127
    if (b < 12) {
        int layer = b / 6;
        int rem   = b % 6;
        int which = rem / 3;
        int r     = rem % 3;
        const float* w = layer ? w2 : w1;
        const float* v = layer ? (which ? k2 : q2) : (which ? k1 : q1);
        const float* row = w + (r * DIM + i) * DIM;
        float s = 0.f;
#pragma unroll 8
        for (int o = 0; o < DIM; ++o) s += row[o] * v[o];
        wqk[((layer * 2 + which) * 3 + r) * DIM + i] = s;
    } else {
        if (i < 2) {
            const float* we = i ? we2 : we1;
            const float* e  = i ? e2  : e1;
            float s = 0.f;
            for (int f = 0; f < DIM; ++f) s += we[f] * e[f];
            cc[i] = s;
        }
    }
}

// ---------------- x fp32 -> bf16 ----------------
__global__ __launch_bounds__(256) void xconv_k(const float* __restrict__ x,
                                               unsigned short* __restrict__ xbf, int total4)
{
    int i = blockIdx.x * 256 + threadIdx.x;
    if (i >= total4) return;
    float4 v = *(const float4*)(x + (size_t)i * 4);
    unsigned short o0 = f2bf(v.x), o1 = f2bf(v.y), o2 = f2bf(v.z), o3 = f2bf(v.w);
    unsigned long long pk = (unsigned long long)o0 | ((unsigned long long)o1 << 16)
                          | ((unsigned long long)o2 << 32) | ((unsigned long long)o3 << 48);
    *(unsigned long long*)(xbf + (size_t)i * 4) = pk;
}

// ---------------- weights -> MFMA-fragment-ordered bf16 ----------------
__global__ void wconv_k(const float* __restrict__ w1, const float* __restrict__ w2,
                        unsigned short* __restrict__ Bf)
{
    int b = blockIdx.x;            // 0..191
    int lane = threadIdx.x;        // 0..63
    int layer = b / 96;
    int rem   = b % 96;
    int ks = rem / 8, f = rem % 8;
    const float* w = layer ? w2 : w1;
    int col  = f * 16 + (lane & 15);
    int krow = ks * 32 + (lane >> 4) * 8;
    unsigned short tmp[8];
#pragma unroll
    for (int j = 0; j < 8; ++j) tmp[j] = f2bf(w[(size_t)(krow + j) * 128 + col]);
    unsigned long long* dst = (unsigned long long*)(Bf + ((size_t)b * 64 + lane) * 8);
    dst[0] = *(unsigned long long*)&tmp[0];
    dst[1] = *(unsigned long long*)&tmp[4];
}

// ---------------- node logits from bf16 features ----------------
__global__ __launch_bounds__(256) void logits_k(const unsigned short* __restrict__ xbf,
    const float* __restrict__ wq, const float* __restrict__ wk,
    float* __restrict__ nq3, float* __restrict__ nk3, int N)
{
    int lane = threadIdx.x & 63;
    int n = blockIdx.x * 4 + (threadIdx.x >> 6);
    if (n >= N) return;
    unsigned int xv = *(const unsigned int*)(xbf + (size_t)n * DIM + lane * 2);
    float x0 = bf2f((unsigned short)(xv & 0xFFFF));
    float x1 = bf2f((unsigned short)(xv >> 16));
#pragma unroll
    for (int r = 0; r < 3; ++r) {
        float2 qv = *(const float2*)(wq + r * DIM + lane * 2);
        float2 kv = *(const float2*)(wk + r * DIM + lane * 2);
        float dq = x0 * qv.x + x1 * qv.y;
        float dk = x0 * kv.x + x1 * kv.y;
#pragma unroll
        for (int off = 32; off > 0; off >>= 1) {
            dq += __shfl_xor(dq, off);
            dk += __shfl_xor(dk, off);
        }
        if (lane == 0) { nq3[n * 3 + r] = dq; nk3[n * 3 + r] = dk; }
    }
}

// ---------------- CSR build over (dst,rel) buckets: 3N entries ----------------
__global__ void hist_k(const int* __restrict__ dst, const int* __restrict__ et,
                       int* __restrict__ hist3, int E)
{
    int e = blockIdx.x * blockDim.x + threadIdx.x;
    if (e < E) atomicAdd(&hist3[dst[e] * 3 + et[e]], 1);
}

__global__ void scan1_k(const int* __restrict__ hist, int* __restrict__ bsum, int N)
{
    __shared__ int ws[4];
    int i = blockIdx.x * 256 + threadIdx.x;
    int v = (i < N) ? hist[i] : 0;
#pragma unroll
    for (int off = 32; off > 0; off >>= 1) v += __shfl_xor(v, off);
    if ((threadIdx.x & 63) == 0) ws[threadIdx.x >> 6] = v;
    __syncthreads();
    if (threadIdx.x == 0) bsum[blockIdx.x] = ws[0] + ws[1] + ws[2] + ws[3];
}

__global__ void scan2_k(const int* __restrict__ bsum, int* __restrict__ boff,
                        int* __restrict__ totalp, int nb)
{
    int lane = threadIdx.x;
    int running = 0;
    for (int base = 0; base < nb; base += 64) {
        int i = base + lane;
        int v = (i < nb) ? bsum[i] : 0;
        int s = v;
#pragma unroll
        for (int off = 1; off < 64; off <<= 1) {
            int t = __shfl_up(s, off);
            if (lane >= off) s += t;
        }
        if (i < nb) boff[i] = running + (s - v);
        running += __shfl(s, 63);
    }
    if (lane == 0) *totalp = running;
}

__global__ void scan3_k(const int* __restrict__ hist, const int* __restrict__ boff,
                        int* __restrict__ rowstart, int N)
{
    __shared__ int ws[4];
    int tid = threadIdx.x, lane = tid & 63, w = tid >> 6;
    int i = blockIdx.x * 256 + tid;
    int v = (i < N) ? hist[i] : 0;
    int s = v;
#pragma unroll
    for (int off = 1; off < 64; off <<= 1) {
        int t = __shfl_up(s, off);
        if (lane >= off) s += t;
    }
    if (lane == 63) ws[w] = s;
    __syncthreads();
    int woff = 0;
    for (int k = 0; k < w; ++k) woff += ws[k];
    if (i < N) rowstart[i] = boff[blockIdx.x] + woff + (s - v);
}

__global__ void fill_k(const int* __restrict__ src, const int* __restrict__ dst,
                       const int* __restrict__ et, const float* __restrict__ ea,
                       const int* __restrict__ rowstart3,
                       int* __restrict__ cursor3, int* __restrict__ packed,
                       float* __restrict__ ea_s, int* __restrict__ dst_s, int E)
{
    int e = blockIdx.x * blockDim.x + threadIdx.x;
    if (e >= E) return;
    int d = dst[e], t = et[e];
    int b3 = d * 3 + t;
    int pos = atomicAdd(&cursor3[b3], 1);
    int slot = rowstart3[b3] + pos;
    packed[slot] = src[e];
    ea_s[slot] = ea[e];
    dst_s[slot] = d;
}

// ---------------- per-slot softmax numerator: ex_s[sl] ----------------
__global__ __launch_bounds__(256) void edgeex_k(const int* __restrict__ packed,
    const float* __restrict__ ea_s, const int* __restrict__ dst_s,
    const int* __restrict__ rowstart3,
    const float* __restrict__ nq3, const float* __restrict__ nk3,
    const float* __restrict__ cc, int cidx,
    float* __restrict__ ex_s, int E)
{
    int sl = blockIdx.x * 256 + threadIdx.x;
    if (sl >= E) return;
    int srcn = packed[sl];
    int d    = dst_s[sl];
    int b3 = d * 3;
    int t = (sl >= rowstart3[b3 + 1]) + (sl >= rowstart3[b3 + 2]);
    float z = nq3[b3 + t] + nk3[srcn * 3 + t] + ea_s[sl] * cc[cidx];
    float a = z > 0.f ? z : 0.2f * z;
    ex_s[sl] = __expf(a);
}

// ---------------- aggregation: wave per dst node, quarter-wave per edge ----------------
// Each 16-lane quarter q handles edge slot i+q with a 16B/lane gather (16x16B = 256B row).
__global__ __launch_bounds__(256) void agg_k(const unsigned short* __restrict__ xbf,
    const int* __restrict__ packed, const float* __restrict__ ex_s,
    const int* __restrict__ rowstart3,
    unsigned short* __restrict__ aggbf, int N)
{
    int tid  = threadIdx.x;
    int lane = tid & 63;
    int n = blockIdx.x * 4 + (tid >> 6);
    if (n >= N) return;
    int q  = lane >> 4;      // quarter index 0..3 (edge i+q)
    int fl = lane & 15;      // feature lane: features fl*8 .. fl*8+7
    int b3 = n * 3;
    int rs0 = rowstart3[b3 + 0], rs1 = rowstart3[b3 + 1];
    int rs2 = rowstart3[b3 + 2], rs3 = rowstart3[b3 + 3];
    float den = 0.f;
    float a0[8], a1[8], a2[8];
#pragma unroll
    for (int j = 0; j < 8; ++j) { a0[j] = 0.f; a1[j] = 0.f; a2[j] = 0.f; }
    const unsigned short* xq = xbf + fl * 8;

#define SEG(S, E_, ACC)                                                     \
    for (int i = (S); i < (E_); i += 4) {                                   \
        int sl = i + q;                                                     \
        bool act = sl < (E_);                                               \
        sl = act ? sl : (E_) - 1;                                           \
        float ex = act ? ex_s[sl] : 0.f;                                    \
        int srcn = packed[sl];                                              \
        short8 xv = *(const short8*)(xq + (size_t)srcn * DIM);              \
        den += ex;                                                          \
        _Pragma("unroll")                                                   \
        for (int j = 0; j < 8; ++j)                                         \
            ACC[j] += ex * bf2f((unsigned short)xv[j]);                     \
    }

    SEG(rs0, rs1, a0)
    SEG(rs1, rs2, a1)
    SEG(rs2, rs3, a2)
#undef SEG

    // reduce across the 4 quarters (lanes differing in bits 4,5)
#pragma unroll
    for (int j = 0; j < 8; ++j) {
        a0[j] += __shfl_xor(a0[j], 16); a0[j] += __shfl_xor(a0[j], 32);
        a1[j] += __shfl_xor(a1[j], 16); a1[j] += __shfl_xor(a1[j], 32);
        a2[j] += __shfl_xor(a2[j], 16); a2[j] += __shfl_xor(a2[j], 32);
    }
    den += __shfl_xor(den, 16);
    den += __shfl_xor(den, 32);
    float inv = 1.f / (den + 1e-16f);

    if (q == 0) {
        unsigned short* dp = aggbf + (size_t)n * 384 + fl * 8;
#define PACKSTORE(A, OFF)                                                   \
        {                                                                   \
            unsigned int w0 = (unsigned int)f2bf(A[0] * inv) |              \
                              ((unsigned int)f2bf(A[1] * inv) << 16);       \
            unsigned int w1 = (unsigned int)f2bf(A[2] * inv) |              \
                              ((unsigned int)f2bf(A[3] * inv) << 16);       \
            unsigned int w2 = (unsigned int)f2bf(A[4] * inv) |              \
                              ((unsigned int)f2bf(A[5] * inv) << 16);       \
            unsigned int w3 = (unsigned int)f2bf(A[6] * inv) |              \
                              ((unsigned int)f2bf(A[7] * inv) << 16);       \
            uint4 u; u.x = w0; u.y = w1; u.z = w2; u.w = w3;                \
            *(uint4*)(dp + (OFF)) = u;                                      \
        }
        PACKSTORE(a0, 0)
        PACKSTORE(a1, 128)
        PACKSTORE(a2, 256)
#undef PACKSTORE
    }
}

// ---------------- MFMA GEMM: C[M,128] = A[M,384]bf16 @ Bfrag + bias ----------------
template <int RELU>
__global__ __launch_bounds__(256) void gemm_mfma_k(const unsigned short* __restrict__ A,
    const unsigned short* __restrict__ Bf, const float* __restrict__ bias,
    unsigned short* __restrict__ hbf, float* __restrict__ out, int M)
{
    int wid  = threadIdx.x >> 6;
    int lane = threadIdx.x & 63;
    int mrow = blockIdx.x * 64 + wid * 16 + (lane & 15);
    int kl   = (lane >> 4) * 8;
    f32x4 acc[8];
#pragma unroll
    for (int f = 0; f < 8; ++f) acc[f] = (f32x4){0.f, 0.f, 0.f, 0.f};
    const unsigned short* arow = A + (size_t)mrow * 384 + kl;
    for (int ks = 0; ks < 12; ++ks) {
        short8 af = *(const short8*)(arow + ks * 32);
        const short8* bp = (const short8*)(Bf + ((size_t)(ks * 8) * 64 + lane) * 8);
#pragma unroll
        for (int f = 0; f < 8; ++f) {
            short8 bfr = bp[f * 64];
            acc[f] = __builtin_amdgcn_mfma_f32_16x16x32_bf16(af, bfr, acc[f], 0, 0, 0);
        }
    }
    int r0  = blockIdx.x * 64 + wid * 16 + (lane >> 4) * 4;
    int cl  = lane & 15;
#pragma unroll
    for (int f = 0; f < 8; ++f) {
        int col = f * 16 + cl;
        float bv = bias[col];
#pragma unroll
        for (int j = 0; j < 4; ++j) {
            int row = r0 + j;
            if (row < M) {
                float v = acc[f][j] + bv;
                if (RELU) {
                    v = v > 0.f ? v : 0.f;
                    hbf[(size_t)row * 128 + col] = f2bf(v);
                } else {
                    out[(size_t)row * 128 + col] = v;
                }
            }
        }
    }
}

// ---------------- host ----------------
extern "C" void kernel_launch(void* const* d_in, const int* in_sizes, int n_in,
                              void* d_out, int out_size, void* d_ws, size_t ws_size,
                              hipStream_t stream)
{
    const float* x   = (const float*)d_in[0];
    const int*   ei  = (const int*)d_in[1];
    const int*   etp = (const int*)d_in[2];
    const float* ea  = (const float*)d_in[3];
    const float* w1  = (const float*)d_in[4];
    const float* q1  = (const float*)d_in[5];
    const float* k1  = (const float*)d_in[6];
    const float* e1  = (const float*)d_in[7];
    const float* we1 = (const float*)d_in[8];
    const float* b1  = (const float*)d_in[9];
    const float* w2  = (const float*)d_in[10];
    const float* q2  = (const float*)d_in[11];
    const float* k2  = (const float*)d_in[12];
    const float* e2  = (const float*)d_in[13];
    const float* we2 = (const float*)d_in[14];
    const float* b2  = (const float*)d_in[15];
    float* out = (float*)d_out;

    const int N = in_sizes[0] / DIM;
    const int E = in_sizes[2];
    const int N3 = N * 3;
    const int* srcp = ei;
    const int* dstp = ei + E;

    int mb64 = (N + 63) / 64;
    int Mpad = mb64 * 64;

    char* base = (char*)d_ws;
    size_t off = 0;
    auto alloc = [&](size_t bytes) -> char* {
        char* p = base + off;
        off = (off + bytes + 255) & ~(size_t)255;
        return p;
    };
    int*   hist3   = (int*)  alloc((size_t)N3 * 4);
    int*   cursor3 = (int*)  alloc((size_t)N3 * 4);
    size_t zero_end = off;
    int*   rowstart3 = (int*)alloc((size_t)(N3 + 1) * 4);
    int*   bsum    = (int*)  alloc(1024 * 4);
    int*   boff    = (int*)  alloc(1024 * 4);
    float* wqk     = (float*)alloc(1536 * 4);
    float* cc      = (float*)alloc(2 * 4);
    float* nq3     = (float*)alloc((size_t)N * 3 * 4);
    float* nk3     = (float*)alloc((size_t)N * 3 * 4);
    int*   packed  = (int*)  alloc((size_t)E * 4);
    float* ea_s    = (float*)alloc((size_t)E * 4);
    int*   dst_s   = (int*)  alloc((size_t)E * 4);
    float* ex_s    = (float*)alloc((size_t)E * 4);
    unsigned short* xbf   = (unsigned short*)alloc((size_t)N * DIM * 2);
    unsigned short* hbf   = (unsigned short*)alloc((size_t)N * DIM * 2);
    unsigned short* aggbf = (unsigned short*)alloc((size_t)Mpad * 384 * 2);
    unsigned short* Bf    = (unsigned short*)alloc((size_t)2 * 96 * 64 * 8 * 2);
    (void)ws_size; (void)n_in; (void)out_size;

    hipMemsetAsync(base, 0, zero_end, stream);
    precompute_k<<<13, 128, 0, stream>>>(w1, q1, k1, e1, we1,
                                         w2, q2, k2, e2, we2, wqk, cc);
    int eb  = (E + 255) / 256;
    int nb4 = (N + 3) / 4;
    int sb3 = (N3 + 255) / 256;
    int total4 = N * DIM / 4;

    xconv_k<<<(total4 + 255) / 256, 256, 0, stream>>>(x, xbf, total4);
    wconv_k<<<192, 64, 0, stream>>>(w1, w2, Bf);

    hist_k<<<eb, 256, 0, stream>>>(dstp, etp, hist3, E);
    scan1_k<<<sb3, 256, 0, stream>>>(hist3, bsum, N3);
    scan2_k<<<1, 64, 0, stream>>>(bsum, boff, rowstart3 + N3, sb3);
    scan3_k<<<sb3, 256, 0, stream>>>(hist3, boff, rowstart3, N3);
    fill_k<<<eb, 256, 0, stream>>>(srcp, dstp, etp, ea, rowstart3, cursor3,
                                   packed, ea_s, dst_s, E);

    const unsigned short* Bf2 = Bf + (size_t)96 * 64 * 8;

    // layer 1
    logits_k<<<nb4, 256, 0, stream>>>(xbf, wqk + 0, wqk + 384, nq3, nk3, N);
    edgeex_k<<<eb, 256, 0, stream>>>(packed, ea_s, dst_s, rowstart3, nq3, nk3, cc, 0, ex_s, E);
    agg_k<<<nb4, 256, 0, stream>>>(xbf, packed, ex_s, rowstart3, aggbf, N);
    gemm_mfma_k<1><<<mb64, 256, 0, stream>>>(aggbf, Bf, b1, hbf, nullptr, N);

    // layer 2
    logits_k<<<nb4, 256, 0, stream>>>(hbf, wqk + 768, wqk + 1152, nq3, nk3, N);
    edgeex_k<<<eb, 256, 0, stream>>>(packed, ea_s, dst_s, rowstart3, nq3, nk3, cc, 1, ex_s, E);
    agg_k<<<nb4, 256, 0, stream>>>(hbf, packed, ex_s, rowstart3, aggbf, N);
    gemm_mfma_k<0><<<mb64, 256, 0, stream>>>(aggbf, Bf2, b2, nullptr, out, N);
}

// Round 13
// 398.661 us; speedup vs baseline: 3.3459x; 1.0361x over previous
//
#include <hip/hip_runtime.h>

#define DIM 128

typedef __attribute__((ext_vector_type(8))) short short8;
typedef __attribute__((ext_vector_type(4))) float f32x4;
typedef unsigned long long u64;

__device__ inline float bf2f(unsigned short u) {
    union { unsigned int i; float f; } v; v.i = (unsigned int)u << 16; return v.f;
}
__device__ inline unsigned short f2bf(float f) {
    union { float f; unsigned int i; } v; v.f = f;
    return (unsigned short)((v.i + 0x7FFF + ((v.i >> 16) & 1)) >> 16);
}

// ---------------- precompute: wq[r]=w[r]@q, wk[r]=w[r]@k, c=we·e (all fp32) ----------------
__global__ void precompute_k(const float* __restrict__ w1, const float* __restrict__ q1,
                             const float* __restrict__ k1, const float* __restrict__ e1,
                             const float* __restrict__ we1,
                             const float* __restrict__ w2, const float* __restrict__ q2,
                             const float* __restrict__ k2, const float* __restrict__ e2,
                             const float* __restrict__ we2,
                             float* __restrict__ wqk,   // [2][2][3][128]
                             float* __restrict__ cc)    // [2]
{
    int b = blockIdx.x;
    int i = threadIdx.x;   // 0..127
    if (b < 12) {
        int layer = b / 6;
        int rem   = b % 6;
        int which = rem / 3;
        int r     = rem % 3;
        const float* w = layer ? w2 : w1;
        const float* v = layer ? (which ? k2 : q2) : (which ? k1 : q1);
        const float* row = w + (r * DIM + i) * DIM;
        float s = 0.f;
#pragma unroll 8
        for (int o = 0; o < DIM; ++o) s += row[o] * v[o];
        wqk[((layer * 2 + which) * 3 + r) * DIM + i] = s;
    } else {
        if (i < 2) {
            const float* we = i ? we2 : we1;
            const float* e  = i ? e2  : e1;
            float s = 0.f;
            for (int f = 0; f < DIM; ++f) s += we[f] * e[f];
            cc[i] = s;
        }
    }
}

// ---------------- weights -> MFMA-fragment-ordered bf16 ----------------
__global__ void wconv_k(const float* __restrict__ w1, const float* __restrict__ w2,
                        unsigned short* __restrict__ Bf)
{
    int b = blockIdx.x;            // 0..191
    int lane = threadIdx.x;        // 0..63
    int layer = b / 96;
    int rem   = b % 96;
    int ks = rem / 8, f = rem % 8;
    const float* w = layer ? w2 : w1;
    int col  = f * 16 + (lane & 15);
    int krow = ks * 32 + (lane >> 4) * 8;
    unsigned short tmp[8];
#pragma unroll
    for (int j = 0; j < 8; ++j) tmp[j] = f2bf(w[(size_t)(krow + j) * 128 + col]);
    u64* dst = (u64*)(Bf + ((size_t)b * 64 + lane) * 8);
    dst[0] = *(u64*)&tmp[0];
    dst[1] = *(u64*)&tmp[4];
}

// ---------------- fused x fp32 -> bf16 + layer-1 node logits ----------------
__global__ __launch_bounds__(256) void xlogits_k(const float* __restrict__ x,
    const float* __restrict__ wq, const float* __restrict__ wk,
    unsigned short* __restrict__ xbf,
    float* __restrict__ nq3, float* __restrict__ nk3, int N)
{
    int lane = threadIdx.x & 63;
    int n = blockIdx.x * 4 + (threadIdx.x >> 6);
    if (n >= N) return;
    float2 xv2 = *(const float2*)(x + (size_t)n * DIM + lane * 2);
    unsigned short o0 = f2bf(xv2.x), o1 = f2bf(xv2.y);
    *(unsigned int*)(xbf + (size_t)n * DIM + lane * 2) =
        (unsigned int)o0 | ((unsigned int)o1 << 16);
    float x0 = bf2f(o0), x1 = bf2f(o1);
#pragma unroll
    for (int r = 0; r < 3; ++r) {
        float2 qv = *(const float2*)(wq + r * DIM + lane * 2);
        float2 kv = *(const float2*)(wk + r * DIM + lane * 2);
        float dq = x0 * qv.x + x1 * qv.y;
        float dk = x0 * kv.x + x1 * kv.y;
#pragma unroll
        for (int off = 32; off > 0; off >>= 1) {
            dq += __shfl_xor(dq, off);
            dk += __shfl_xor(dk, off);
        }
        if (lane == 0) { nq3[n * 3 + r] = dq; nk3[n * 3 + r] = dk; }
    }
}

// ---------------- node logits from bf16 features (layer 2) ----------------
__global__ __launch_bounds__(256) void logits_k(const unsigned short* __restrict__ xbf,
    const float* __restrict__ wq, const float* __restrict__ wk,
    float* __restrict__ nq3, float* __restrict__ nk3, int N)
{
    int lane = threadIdx.x & 63;
    int n = blockIdx.x * 4 + (threadIdx.x >> 6);
    if (n >= N) return;
    unsigned int xv = *(const unsigned int*)(xbf + (size_t)n * DIM + lane * 2);
    float x0 = bf2f((unsigned short)(xv & 0xFFFF));
    float x1 = bf2f((unsigned short)(xv >> 16));
#pragma unroll
    for (int r = 0; r < 3; ++r) {
        float2 qv = *(const float2*)(wq + r * DIM + lane * 2);
        float2 kv = *(const float2*)(wk + r * DIM + lane * 2);
        float dq = x0 * qv.x + x1 * qv.y;
        float dk = x0 * kv.x + x1 * kv.y;
#pragma unroll
        for (int off = 32; off > 0; off >>= 1) {
            dq += __shfl_xor(dq, off);
            dk += __shfl_xor(dk, off);
        }
        if (lane == 0) { nq3[n * 3 + r] = dq; nk3[n * 3 + r] = dk; }
    }
}

// ---------------- CSR build over (dst,rel) buckets: 3N entries ----------------
__global__ void hist_k(const int* __restrict__ dst, const int* __restrict__ et,
                       int* __restrict__ hist3, int E)
{
    int e = blockIdx.x * blockDim.x + threadIdx.x;
    if (e < E) atomicAdd(&hist3[dst[e] * 3 + et[e]], 1);
}

__global__ void scan1_k(const int* __restrict__ hist, int* __restrict__ bsum, int N)
{
    __shared__ int ws[4];
    int i = blockIdx.x * 256 + threadIdx.x;
    int v = (i < N) ? hist[i] : 0;
#pragma unroll
    for (int off = 32; off > 0; off >>= 1) v += __shfl_xor(v, off);
    if ((threadIdx.x & 63) == 0) ws[threadIdx.x >> 6] = v;
    __syncthreads();
    if (threadIdx.x == 0) bsum[blockIdx.x] = ws[0] + ws[1] + ws[2] + ws[3];
}

__global__ void scan2_k(const int* __restrict__ bsum, int* __restrict__ boff,
                        int* __restrict__ totalp, int nb)
{
    int lane = threadIdx.x;
    int running = 0;
    for (int base = 0; base < nb; base += 64) {
        int i = base + lane;
        int v = (i < nb) ? bsum[i] : 0;
        int s = v;
#pragma unroll
        for (int off = 1; off < 64; off <<= 1) {
            int t = __shfl_up(s, off);
            if (lane >= off) s += t;
        }
        if (i < nb) boff[i] = running + (s - v);
        running += __shfl(s, 63);
    }
    if (lane == 0) *totalp = running;
}

__global__ void scan3_k(const int* __restrict__ hist, const int* __restrict__ boff,
                        int* __restrict__ rowstart, int N)
{
    __shared__ int ws[4];
    int tid = threadIdx.x, lane = tid & 63, w = tid >> 6;
    int i = blockIdx.x * 256 + tid;
    int v = (i < N) ? hist[i] : 0;
    int s = v;
#pragma unroll
    for (int off = 1; off < 64; off <<= 1) {
        int t = __shfl_up(s, off);
        if (lane >= off) s += t;
    }
    if (lane == 63) ws[w] = s;
    __syncthreads();
    int woff = 0;
    for (int k = 0; k < w; ++k) woff += ws[k];
    if (i < N) rowstart[i] = boff[blockIdx.x] + woff + (s - v);
}

// ---------------- fill: ONE 8B scattered payload per edge ----------------
// payload = src(17b) | t<<17 (2b) | d<<19 (17b) | bf16(ea)<<48
__global__ void fill_k(const int* __restrict__ src, const int* __restrict__ dst,
                       const int* __restrict__ et, const float* __restrict__ ea,
                       const int* __restrict__ rowstart3,
                       int* __restrict__ cursor3, u64* __restrict__ pay, int E)
{
    int e = blockIdx.x * blockDim.x + threadIdx.x;
    if (e >= E) return;
    int d = dst[e], t = et[e];
    int b3 = d * 3 + t;
    int pos = atomicAdd(&cursor3[b3], 1);
    int slot = rowstart3[b3] + pos;
    u64 p = (u64)(unsigned)src[e] | ((u64)(unsigned)t << 17)
          | ((u64)(unsigned)d << 19) | ((u64)f2bf(ea[e]) << 48);
    pay[slot] = p;
}

// ---------------- per-slot softmax numerator: ex_s[sl] ----------------
__global__ __launch_bounds__(256) void edgeex_k(const u64* __restrict__ pay,
    const float* __restrict__ nq3, const float* __restrict__ nk3,
    const float* __restrict__ cc, int cidx,
    float* __restrict__ ex_s, int E)
{
    int sl = blockIdx.x * 256 + threadIdx.x;
    if (sl >= E) return;
    u64 p = pay[sl];
    int srcn = (int)(p & 0x1FFFF);
    int t    = (int)((p >> 17) & 3);
    int d    = (int)((p >> 19) & 0x1FFFF);
    float eav = bf2f((unsigned short)(p >> 48));
    float z = nq3[d * 3 + t] + nk3[srcn * 3 + t] + eav * cc[cidx];
    float a = z > 0.f ? z : 0.2f * z;
    ex_s[sl] = __expf(a);
}

// ---------------- aggregation: wave per dst node, quarter-wave per edge ----------------
__global__ __launch_bounds__(256) void agg_k(const unsigned short* __restrict__ xbf,
    const u64* __restrict__ pay, const float* __restrict__ ex_s,
    const int* __restrict__ rowstart3,
    unsigned short* __restrict__ aggbf, int N)
{
    int tid  = threadIdx.x;
    int lane = tid & 63;
    int n = blockIdx.x * 4 + (tid >> 6);
    if (n >= N) return;
    int q  = lane >> 4;      // quarter index 0..3 (edge i+q)
    int fl = lane & 15;      // feature lane: features fl*8 .. fl*8+7
    int b3 = n * 3;
    int rs0 = rowstart3[b3 + 0], rs1 = rowstart3[b3 + 1];
    int rs2 = rowstart3[b3 + 2], rs3 = rowstart3[b3 + 3];
    float den = 0.f;
    float a0[8], a1[8], a2[8];
#pragma unroll
    for (int j = 0; j < 8; ++j) { a0[j] = 0.f; a1[j] = 0.f; a2[j] = 0.f; }
    const unsigned short* xq = xbf + fl * 8;

#define SEG(S, E_, ACC)                                                     \
    for (int i = (S); i < (E_); i += 4) {                                   \
        int sl = i + q;                                                     \
        bool act = sl < (E_);                                               \
        sl = act ? sl : (E_) - 1;                                           \
        float ex = act ? ex_s[sl] : 0.f;                                    \
        int srcn = (int)(pay[sl] & 0x1FFFF);                                \
        short8 xv = *(const short8*)(xq + (size_t)srcn * DIM);              \
        den += ex;                                                          \
        _Pragma("unroll")                                                   \
        for (int j = 0; j < 8; ++j)                                         \
            ACC[j] += ex * bf2f((unsigned short)xv[j]);                     \
    }

    SEG(rs0, rs1, a0)
    SEG(rs1, rs2, a1)
    SEG(rs2, rs3, a2)
#undef SEG

    // reduce across the 4 quarters (lanes differing in bits 4,5)
#pragma unroll
    for (int j = 0; j < 8; ++j) {
        a0[j] += __shfl_xor(a0[j], 16); a0[j] += __shfl_xor(a0[j], 32);
        a1[j] += __shfl_xor(a1[j], 16); a1[j] += __shfl_xor(a1[j], 32);
        a2[j] += __shfl_xor(a2[j], 16); a2[j] += __shfl_xor(a2[j], 32);
    }
    den += __shfl_xor(den, 16);
    den += __shfl_xor(den, 32);
    float inv = 1.f / (den + 1e-16f);

    if (q == 0) {
        unsigned short* dp = aggbf + (size_t)n * 384 + fl * 8;
#define PACKSTORE(A, OFF)                                                   \
        {                                                                   \
            unsigned int w0 = (unsigned int)f2bf(A[0] * inv) |              \
                              ((unsigned int)f2bf(A[1] * inv) << 16);       \
            unsigned int w1 = (unsigned int)f2bf(A[2] * inv) |              \
                              ((unsigned int)f2bf(A[3] * inv) << 16);       \
            unsigned int w2 = (unsigned int)f2bf(A[4] * inv) |              \
                              ((unsigned int)f2bf(A[5] * inv) << 16);       \
            unsigned int w3 = (unsigned int)f2bf(A[6] * inv) |              \
                              ((unsigned int)f2bf(A[7] * inv) << 16);       \
            uint4 u; u.x = w0; u.y = w1; u.z = w2; u.w = w3;                \
            *(uint4*)(dp + (OFF)) = u;                                      \
        }
        PACKSTORE(a0, 0)
        PACKSTORE(a1, 128)
        PACKSTORE(a2, 256)
#undef PACKSTORE
    }
}

// ---------------- MFMA GEMM: C[M,128] = A[M,384]bf16 @ Bfrag + bias ----------------
template <int RELU>
__global__ __launch_bounds__(256) void gemm_mfma_k(const unsigned short* __restrict__ A,
    const unsigned short* __restrict__ Bf, const float* __restrict__ bias,
    unsigned short* __restrict__ hbf, float* __restrict__ out, int M)
{
    int wid  = threadIdx.x >> 6;
    int lane = threadIdx.x & 63;
    int mrow = blockIdx.x * 64 + wid * 16 + (lane & 15);
    int kl   = (lane >> 4) * 8;
    f32x4 acc[8];
#pragma unroll
    for (int f = 0; f < 8; ++f) acc[f] = (f32x4){0.f, 0.f, 0.f, 0.f};
    const unsigned short* arow = A + (size_t)mrow * 384 + kl;
    for (int ks = 0; ks < 12; ++ks) {
        short8 af = *(const short8*)(arow + ks * 32);
        const short8* bp = (const short8*)(Bf + ((size_t)(ks * 8) * 64 + lane) * 8);
#pragma unroll
        for (int f = 0; f < 8; ++f) {
            short8 bfr = bp[f * 64];
            acc[f] = __builtin_amdgcn_mfma_f32_16x16x32_bf16(af, bfr, acc[f], 0, 0, 0);
        }
    }
    int r0  = blockIdx.x * 64 + wid * 16 + (lane >> 4) * 4;
    int cl  = lane & 15;
#pragma unroll
    for (int f = 0; f < 8; ++f) {
        int col = f * 16 + cl;
        float bv = bias[col];
#pragma unroll
        for (int j = 0; j < 4; ++j) {
            int row = r0 + j;
            if (row < M) {
                float v = acc[f][j] + bv;
                if (RELU) {
                    v = v > 0.f ? v : 0.f;
                    hbf[(size_t)row * 128 + col] = f2bf(v);
                } else {
                    out[(size_t)row * 128 + col] = v;
                }
            }
        }
    }
}

// ---------------- host ----------------
extern "C" void kernel_launch(void* const* d_in, const int* in_sizes, int n_in,
                              void* d_out, int out_size, void* d_ws, size_t ws_size,
                              hipStream_t stream)
{
    const float* x   = (const float*)d_in[0];
    const int*   ei  = (const int*)d_in[1];
    const int*   etp = (const int*)d_in[2];
    const float* ea  = (const float*)d_in[3];
    const float* w1  = (const float*)d_in[4];
    const float* q1  = (const float*)d_in[5];
    const float* k1  = (const float*)d_in[6];
    const float* e1  = (const float*)d_in[7];
    const float* we1 = (const float*)d_in[8];
    const float* b1  = (const float*)d_in[9];
    const float* w2  = (const float*)d_in[10];
    const float* q2  = (const float*)d_in[11];
    const float* k2  = (const float*)d_in[12];
    const float* e2  = (const float*)d_in[13];
    const float* we2 = (const float*)d_in[14];
    const float* b2  = (const float*)d_in[15];
    float* out = (float*)d_out;

    const int N = in_sizes[0] / DIM;
    const int E = in_sizes[2];
    const int N3 = N * 3;
    const int* srcp = ei;
    const int* dstp = ei + E;

    int mb64 = (N + 63) / 64;
    int Mpad = mb64 * 64;

    char* base = (char*)d_ws;
    size_t off = 0;
    auto alloc = [&](size_t bytes) -> char* {
        char* p = base + off;
        off = (off + bytes + 255) & ~(size_t)255;
        return p;
    };
    int*   hist3   = (int*)  alloc((size_t)N3 * 4);
    int*   cursor3 = (int*)  alloc((size_t)N3 * 4);
    size_t zero_end = off;
    int*   rowstart3 = (int*)alloc((size_t)(N3 + 1) * 4);
    int*   bsum    = (int*)  alloc(1024 * 4);
    int*   boff    = (int*)  alloc(1024 * 4);
    float* wqk     = (float*)alloc(1536 * 4);
    float* cc      = (float*)alloc(2 * 4);
    float* nq3     = (float*)alloc((size_t)N * 3 * 4);
    float* nk3     = (float*)alloc((size_t)N * 3 * 4);
    u64*   pay     = (u64*)  alloc((size_t)E * 8);
    float* ex_s    = (float*)alloc((size_t)E * 4);
    unsigned short* xbf   = (unsigned short*)alloc((size_t)N * DIM * 2);
    unsigned short* hbf   = (unsigned short*)alloc((size_t)N * DIM * 2);
    unsigned short* aggbf = (unsigned short*)alloc((size_t)Mpad * 384 * 2);
    unsigned short* Bf    = (unsigned short*)alloc((size_t)2 * 96 * 64 * 8 * 2);
    (void)ws_size; (void)n_in; (void)out_size;

    hipMemsetAsync(base, 0, zero_end, stream);
    precompute_k<<<13, 128, 0, stream>>>(w1, q1, k1, e1, we1,
                                         w2, q2, k2, e2, we2, wqk, cc);
    int eb  = (E + 255) / 256;
    int nb4 = (N + 3) / 4;
    int sb3 = (N3 + 255) / 256;

    wconv_k<<<192, 64, 0, stream>>>(w1, w2, Bf);

    hist_k<<<eb, 256, 0, stream>>>(dstp, etp, hist3, E);
    scan1_k<<<sb3, 256, 0, stream>>>(hist3, bsum, N3);
    scan2_k<<<1, 64, 0, stream>>>(bsum, boff, rowstart3 + N3, sb3);
    scan3_k<<<sb3, 256, 0, stream>>>(hist3, boff, rowstart3, N3);
    fill_k<<<eb, 256, 0, stream>>>(srcp, dstp, etp, ea, rowstart3, cursor3, pay, E);

    const unsigned short* Bf2 = Bf + (size_t)96 * 64 * 8;

    // layer 1 (xconv fused into logits)
    xlogits_k<<<nb4, 256, 0, stream>>>(x, wqk + 0, wqk + 384, xbf, nq3, nk3, N);
    edgeex_k<<<eb, 256, 0, stream>>>(pay, nq3, nk3, cc, 0, ex_s, E);
    agg_k<<<nb4, 256, 0, stream>>>(xbf, pay, ex_s, rowstart3, aggbf, N);
    gemm_mfma_k<1><<<mb64, 256, 0, stream>>>(aggbf, Bf, b1, hbf, nullptr, N);

    // layer 2
    logits_k<<<nb4, 256, 0, stream>>>(hbf, wqk + 768, wqk + 1152, nq3, nk3, N);
    edgeex_k<<<eb, 256, 0, stream>>>(pay, nq3, nk3, cc, 1, ex_s, E);
    agg_k<<<nb4, 256, 0, stream>>>(hbf, pay, ex_s, rowstart3, aggbf, N);
    gemm_mfma_k<0><<<mb64, 256, 0, stream>>>(aggbf, Bf2, b2, nullptr, out, N);
}

// Round 15
// 385.608 us; speedup vs baseline: 3.4592x; 1.0339x over previous
//
#include <hip/hip_runtime.h>

#define DIM 128

typedef __attribute__((ext_vector_type(8))) short short8;
typedef __attribute__((ext_vector_type(4))) float f32x4;
typedef unsigned long long u64;

__device__ inline float bf2f(unsigned short u) {
    union { unsigned int i; float f; } v; v.i = (unsigned int)u << 16; return v.f;
}
__device__ inline unsigned short f2bf(float f) {
    union { float f; unsigned int i; } v; v.f = f;
    return (unsigned short)((v.i + 0x7FFF + ((v.i >> 16) & 1)) >> 16);
}

// ---------------- precompute: wq[r]=w[r]@q, wk[r]=w[r]@k, c=we·e (all fp32) ----------------
__global__ void precompute_k(const float* __restrict__ w1, const float* __restrict__ q1,
                             const float* __restrict__ k1, const float* __restrict__ e1,
                             const float* __restrict__ we1,
                             const float* __restrict__ w2, const float* __restrict__ q2,
                             const float* __restrict__ k2, const float* __restrict__ e2,
                             const float* __restrict__ we2,
                             float* __restrict__ wqk,   // [2][2][3][128]
                             float* __restrict__ cc)    // [2]
{
    int b = blockIdx.x;
    int i = threadIdx.x;   // 0..127
    if (b < 12) {
        int layer = b / 6;
        int rem   = b % 6;
        int which = rem / 3;
        int r     = rem % 3;
        const float* w = layer ? w2 : w1;
        const float* v = layer ? (which ? k2 : q2) : (which ? k1 : q1);
        const float* row = w + (r * DIM + i) * DIM;
        float s = 0.f;
#pragma unroll 8
        for (int o = 0; o < DIM; ++o) s += row[o] * v[o];
        wqk[((layer * 2 + which) * 3 + r) * DIM + i] = s;
    } else {
        if (i < 2) {
            const float* we = i ? we2 : we1;
            const float* e  = i ? e2  : e1;
            float s = 0.f;
            for (int f = 0; f < DIM; ++f) s += we[f] * e[f];
            cc[i] = s;
        }
    }
}

// ---------------- weights -> MFMA-fragment-ordered bf16 ----------------
__global__ void wconv_k(const float* __restrict__ w1, const float* __restrict__ w2,
                        unsigned short* __restrict__ Bf)
{
    int b = blockIdx.x;            // 0..191
    int lane = threadIdx.x;        // 0..63
    int layer = b / 96;
    int rem   = b % 96;
    int ks = rem / 8, f = rem % 8;
    const float* w = layer ? w2 : w1;
    int col  = f * 16 + (lane & 15);
    int krow = ks * 32 + (lane >> 4) * 8;
    unsigned short tmp[8];
#pragma unroll
    for (int j = 0; j < 8; ++j) tmp[j] = f2bf(w[(size_t)(krow + j) * 128 + col]);
    u64* dst = (u64*)(Bf + ((size_t)b * 64 + lane) * 8);
    dst[0] = *(u64*)&tmp[0];
    dst[1] = *(u64*)&tmp[4];
}

// ---------------- fused x fp32 -> bf16 + layer-1 node logits ----------------
__global__ __launch_bounds__(256) void xlogits_k(const float* __restrict__ x,
    const float* __restrict__ wq, const float* __restrict__ wk,
    unsigned short* __restrict__ xbf,
    float* __restrict__ nq3, float* __restrict__ nk3, int N)
{
    int lane = threadIdx.x & 63;
    int n = blockIdx.x * 4 + (threadIdx.x >> 6);
    if (n >= N) return;
    float2 xv2 = *(const float2*)(x + (size_t)n * DIM + lane * 2);
    unsigned short o0 = f2bf(xv2.x), o1 = f2bf(xv2.y);
    *(unsigned int*)(xbf + (size_t)n * DIM + lane * 2) =
        (unsigned int)o0 | ((unsigned int)o1 << 16);
    float x0 = bf2f(o0), x1 = bf2f(o1);
#pragma unroll
    for (int r = 0; r < 3; ++r) {
        float2 qv = *(const float2*)(wq + r * DIM + lane * 2);
        float2 kv = *(const float2*)(wk + r * DIM + lane * 2);
        float dq = x0 * qv.x + x1 * qv.y;
        float dk = x0 * kv.x + x1 * kv.y;
#pragma unroll
        for (int off = 32; off > 0; off >>= 1) {
            dq += __shfl_xor(dq, off);
            dk += __shfl_xor(dk, off);
        }
        if (lane == 0) { nq3[n * 3 + r] = dq; nk3[n * 3 + r] = dk; }
    }
}

// ---------------- node logits from bf16 features (layer 2) ----------------
__global__ __launch_bounds__(256) void logits_k(const unsigned short* __restrict__ xbf,
    const float* __restrict__ wq, const float* __restrict__ wk,
    float* __restrict__ nq3, float* __restrict__ nk3, int N)
{
    int lane = threadIdx.x & 63;
    int n = blockIdx.x * 4 + (threadIdx.x >> 6);
    if (n >= N) return;
    unsigned int xv = *(const unsigned int*)(xbf + (size_t)n * DIM + lane * 2);
    float x0 = bf2f((unsigned short)(xv & 0xFFFF));
    float x1 = bf2f((unsigned short)(xv >> 16));
#pragma unroll
    for (int r = 0; r < 3; ++r) {
        float2 qv = *(const float2*)(wq + r * DIM + lane * 2);
        float2 kv = *(const float2*)(wk + r * DIM + lane * 2);
        float dq = x0 * qv.x + x1 * qv.y;
        float dk = x0 * kv.x + x1 * kv.y;
#pragma unroll
        for (int off = 32; off > 0; off >>= 1) {
            dq += __shfl_xor(dq, off);
            dk += __shfl_xor(dk, off);
        }
        if (lane == 0) { nq3[n * 3 + r] = dq; nk3[n * 3 + r] = dk; }
    }
}

// ---------------- CSR build over (dst,rel) buckets: 3N entries ----------------
__global__ void hist_k(const int* __restrict__ dst, const int* __restrict__ et,
                       int* __restrict__ hist3, int E)
{
    int e = blockIdx.x * blockDim.x + threadIdx.x;
    if (e < E) atomicAdd(&hist3[dst[e] * 3 + et[e]], 1);
}

__global__ void scan1_k(const int* __restrict__ hist, int* __restrict__ bsum, int N)
{
    __shared__ int ws[4];
    int i = blockIdx.x * 256 + threadIdx.x;
    int v = (i < N) ? hist[i] : 0;
#pragma unroll
    for (int off = 32; off > 0; off >>= 1) v += __shfl_xor(v, off);
    if ((threadIdx.x & 63) == 0) ws[threadIdx.x >> 6] = v;
    __syncthreads();
    if (threadIdx.x == 0) bsum[blockIdx.x] = ws[0] + ws[1] + ws[2] + ws[3];
}

__global__ void scan2_k(const int* __restrict__ bsum, int* __restrict__ boff,
                        int* __restrict__ totalp, int nb)
{
    int lane = threadIdx.x;
    int running = 0;
    for (int base = 0; base < nb; base += 64) {
        int i = base + lane;
        int v = (i < nb) ? bsum[i] : 0;
        int s = v;
#pragma unroll
        for (int off = 1; off < 64; off <<= 1) {
            int t = __shfl_up(s, off);
            if (lane >= off) s += t;
        }
        if (i < nb) boff[i] = running + (s - v);
        running += __shfl(s, 63);
    }
    if (lane == 0) *totalp = running;
}

__global__ void scan3_k(const int* __restrict__ hist, const int* __restrict__ boff,
                        int* __restrict__ rowstart, int N)
{
    __shared__ int ws[4];
    int tid = threadIdx.x, lane = tid & 63, w = tid >> 6;
    int i = blockIdx.x * 256 + tid;
    int v = (i < N) ? hist[i] : 0;
    int s = v;
#pragma unroll
    for (int off = 1; off < 64; off <<= 1) {
        int t = __shfl_up(s, off);
        if (lane >= off) s += t;
    }
    if (lane == 63) ws[w] = s;
    __syncthreads();
    int woff = 0;
    for (int k = 0; k < w; ++k) woff += ws[k];
    if (i < N) rowstart[i] = boff[blockIdx.x] + woff + (s - v);
}

// ---------------- fill: XCD-partitioned 8B payload scatter ----------------
// p = blockIdx & 7 targets dst in [N*p/8, N*(p+1)/8): with the default
// round-robin blockIdx->XCD mapping, each slot region is written by ONE XCD
// -> lines stay in its local L2 (no cross-XCD line ping-pong).
// payload = src(17b) | t<<17 (2b) | d<<19 (17b) | bf16(ea)<<48
__global__ void fill_k(const int* __restrict__ src, const int* __restrict__ dst,
                       const int* __restrict__ et, const float* __restrict__ ea,
                       const int* __restrict__ rowstart3,
                       int* __restrict__ cursor3, u64* __restrict__ pay, int E, int N)
{
    int p = blockIdx.x & 7;
    int e = (blockIdx.x >> 3) * 256 + threadIdx.x;
    if (e >= E) return;
    int d = dst[e];
    int plo = (N * p) >> 3;
    int phi = (N * (p + 1)) >> 3;
    if (d < plo || d >= phi) return;
    int t = et[e];
    int b3 = d * 3 + t;
    int pos = atomicAdd(&cursor3[b3], 1);
    int slot = rowstart3[b3] + pos;
    u64 pv = (u64)(unsigned)src[e] | ((u64)(unsigned)t << 17)
           | ((u64)(unsigned)d << 19) | ((u64)f2bf(ea[e]) << 48);
    pay[slot] = pv;
}

// ---------------- per-slot softmax numerator: ex_s[sl] ----------------
__global__ __launch_bounds__(256) void edgeex_k(const u64* __restrict__ pay,
    const float* __restrict__ nq3, const float* __restrict__ nk3,
    const float* __restrict__ cc, int cidx,
    float* __restrict__ ex_s, int E)
{
    int sl = blockIdx.x * 256 + threadIdx.x;
    if (sl >= E) return;
    u64 p = pay[sl];
    int srcn = (int)(p & 0x1FFFF);
    int t    = (int)((p >> 17) & 3);
    int d    = (int)((p >> 19) & 0x1FFFF);
    float eav = bf2f((unsigned short)(p >> 48));
    float z = nq3[d * 3 + t] + nk3[srcn * 3 + t] + eav * cc[cidx];
    float a = z > 0.f ? z : 0.2f * z;
    ex_s[sl] = __expf(a);
}

// ---------------- aggregation: wave per dst node, quarter-wave per edge ----------------
__global__ __launch_bounds__(256) void agg_k(const unsigned short* __restrict__ xbf,
    const u64* __restrict__ pay, const float* __restrict__ ex_s,
    const int* __restrict__ rowstart3,
    unsigned short* __restrict__ aggbf, int N)
{
    int tid  = threadIdx.x;
    int lane = tid & 63;
    int n = blockIdx.x * 4 + (tid >> 6);
    if (n >= N) return;
    int q  = lane >> 4;      // quarter index 0..3 (edge i+q)
    int fl = lane & 15;      // feature lane: features fl*8 .. fl*8+7
    int b3 = n * 3;
    int rs0 = rowstart3[b3 + 0], rs1 = rowstart3[b3 + 1];
    int rs2 = rowstart3[b3 + 2], rs3 = rowstart3[b3 + 3];
    float den = 0.f;
    float a0[8], a1[8], a2[8];
#pragma unroll
    for (int j = 0; j < 8; ++j) { a0[j] = 0.f; a1[j] = 0.f; a2[j] = 0.f; }
    const unsigned short* xq = xbf + fl * 8;

#define SEG(S, E_, ACC)                                                     \
    for (int i = (S); i < (E_); i += 4) {                                   \
        int sl = i + q;                                                     \
        bool act = sl < (E_);                                               \
        sl = act ? sl : (E_) - 1;                                           \
        float ex = act ? ex_s[sl] : 0.f;                                    \
        int srcn = (int)(pay[sl] & 0x1FFFF);                                \
        short8 xv = *(const short8*)(xq + (size_t)srcn * DIM);              \
        den += ex;                                                          \
        _Pragma("unroll")                                                   \
        for (int j = 0; j < 8; ++j)                                         \
            ACC[j] += ex * bf2f((unsigned short)xv[j]);                     \
    }

    SEG(rs0, rs1, a0)
    SEG(rs1, rs2, a1)
    SEG(rs2, rs3, a2)
#undef SEG

    // reduce across the 4 quarters (lanes differing in bits 4,5)
#pragma unroll
    for (int j = 0; j < 8; ++j) {
        a0[j] += __shfl_xor(a0[j], 16); a0[j] += __shfl_xor(a0[j], 32);
        a1[j] += __shfl_xor(a1[j], 16); a1[j] += __shfl_xor(a1[j], 32);
        a2[j] += __shfl_xor(a2[j], 16); a2[j] += __shfl_xor(a2[j], 32);
    }
    den += __shfl_xor(den, 16);
    den += __shfl_xor(den, 32);
    float inv = 1.f / (den + 1e-16f);

    if (q == 0) {
        unsigned short* dp = aggbf + (size_t)n * 384 + fl * 8;
#define PACKSTORE(A, OFF)                                                   \
        {                                                                   \
            unsigned int w0 = (unsigned int)f2bf(A[0] * inv) |              \
                              ((unsigned int)f2bf(A[1] * inv) << 16);       \
            unsigned int w1 = (unsigned int)f2bf(A[2] * inv) |              \
                              ((unsigned int)f2bf(A[3] * inv) << 16);       \
            unsigned int w2 = (unsigned int)f2bf(A[4] * inv) |              \
                              ((unsigned int)f2bf(A[5] * inv) << 16);       \
            unsigned int w3 = (unsigned int)f2bf(A[6] * inv) |              \
                              ((unsigned int)f2bf(A[7] * inv) << 16);       \
            uint4 u; u.x = w0; u.y = w1; u.z = w2; u.w = w3;                \
            *(uint4*)(dp + (OFF)) = u;                                      \
        }
        PACKSTORE(a0, 0)
        PACKSTORE(a1, 128)
        PACKSTORE(a2, 256)
#undef PACKSTORE
    }
}

// ---------------- MFMA GEMM: C[M,128] = A[M,384]bf16 @ Bfrag + bias ----------------
template <int RELU>
__global__ __launch_bounds__(256) void gemm_mfma_k(const unsigned short* __restrict__ A,
    const unsigned short* __restrict__ Bf, const float* __restrict__ bias,
    unsigned short* __restrict__ hbf, float* __restrict__ out, int M)
{
    int wid  = threadIdx.x >> 6;
    int lane = threadIdx.x & 63;
    int mrow = blockIdx.x * 64 + wid * 16 + (lane & 15);
    int kl   = (lane >> 4) * 8;
    f32x4 acc[8];
#pragma unroll
    for (int f = 0; f < 8; ++f) acc[f] = (f32x4){0.f, 0.f, 0.f, 0.f};
    const unsigned short* arow = A + (size_t)mrow * 384 + kl;
    for (int ks = 0; ks < 12; ++ks) {
        short8 af = *(const short8*)(arow + ks * 32);
        const short8* bp = (const short8*)(Bf + ((size_t)(ks * 8) * 64 + lane) * 8);
#pragma unroll
        for (int f = 0; f < 8; ++f) {
            short8 bfr = bp[f * 64];
            acc[f] = __builtin_amdgcn_mfma_f32_16x16x32_bf16(af, bfr, acc[f], 0, 0, 0);
        }
    }
    int r0  = blockIdx.x * 64 + wid * 16 + (lane >> 4) * 4;
    int cl  = lane & 15;
#pragma unroll
    for (int f = 0; f < 8; ++f) {
        int col = f * 16 + cl;
        float bv = bias[col];
#pragma unroll
        for (int j = 0; j < 4; ++j) {
            int row = r0 + j;
            if (row < M) {
                float v = acc[f][j] + bv;
                if (RELU) {
                    v = v > 0.f ? v : 0.f;
                    hbf[(size_t)row * 128 + col] = f2bf(v);
                } else {
                    out[(size_t)row * 128 + col] = v;
                }
            }
        }
    }
}

// ---------------- host ----------------
extern "C" void kernel_launch(void* const* d_in, const int* in_sizes, int n_in,
                              void* d_out, int out_size, void* d_ws, size_t ws_size,
                              hipStream_t stream)
{
    const float* x   = (const float*)d_in[0];
    const int*   ei  = (const int*)d_in[1];
    const int*   etp = (const int*)d_in[2];
    const float* ea  = (const float*)d_in[3];
    const float* w1  = (const float*)d_in[4];
    const float* q1  = (const float*)d_in[5];
    const float* k1  = (const float*)d_in[6];
    const float* e1  = (const float*)d_in[7];
    const float* we1 = (const float*)d_in[8];
    const float* b1  = (const float*)d_in[9];
    const float* w2  = (const float*)d_in[10];
    const float* q2  = (const float*)d_in[11];
    const float* k2  = (const float*)d_in[12];
    const float* e2  = (const float*)d_in[13];
    const float* we2 = (const float*)d_in[14];
    const float* b2  = (const float*)d_in[15];
    float* out = (float*)d_out;

    const int N = in_sizes[0] / DIM;
    const int E = in_sizes[2];
    const int N3 = N * 3;
    const int* srcp = ei;
    const int* dstp = ei + E;

    int mb64 = (N + 63) / 64;
    int Mpad = mb64 * 64;

    char* base = (char*)d_ws;
    size_t off = 0;
    auto alloc = [&](size_t bytes) -> char* {
        char* p = base + off;
        off = (off + bytes + 255) & ~(size_t)255;
        return p;
    };
    int*   hist3   = (int*)  alloc((size_t)N3 * 4);
    int*   cursor3 = (int*)  alloc((size_t)N3 * 4);
    size_t zero_end = off;
    int*   rowstart3 = (int*)alloc((size_t)(N3 + 1) * 4);
    int*   bsum    = (int*)  alloc(1024 * 4);
    int*   boff    = (int*)  alloc(1024 * 4);
    float* wqk     = (float*)alloc(1536 * 4);
    float* cc      = (float*)alloc(2 * 4);
    float* nq3     = (float*)alloc((size_t)N * 3 * 4);
    float* nk3     = (float*)alloc((size_t)N * 3 * 4);
    u64*   pay     = (u64*)  alloc((size_t)E * 8);
    float* ex_s    = (float*)alloc((size_t)E * 4);
    unsigned short* xbf   = (unsigned short*)alloc((size_t)N * DIM * 2);
    unsigned short* hbf   = (unsigned short*)alloc((size_t)N * DIM * 2);
    unsigned short* aggbf = (unsigned short*)alloc((size_t)Mpad * 384 * 2);
    unsigned short* Bf    = (unsigned short*)alloc((size_t)2 * 96 * 64 * 8 * 2);
    (void)ws_size; (void)n_in; (void)out_size;

    hipMemsetAsync(base, 0, zero_end, stream);
    precompute_k<<<13, 128, 0, stream>>>(w1, q1, k1, e1, we1,
                                         w2, q2, k2, e2, we2, wqk, cc);
    int eb  = (E + 255) / 256;
    int nb4 = (N + 3) / 4;
    int sb3 = (N3 + 255) / 256;

    wconv_k<<<192, 64, 0, stream>>>(w1, w2, Bf);

    hist_k<<<eb, 256, 0, stream>>>(dstp, etp, hist3, E);
    scan1_k<<<sb3, 256, 0, stream>>>(hist3, bsum, N3);
    scan2_k<<<1, 64, 0, stream>>>(bsum, boff, rowstart3 + N3, sb3);
    scan3_k<<<sb3, 256, 0, stream>>>(hist3, boff, rowstart3, N3);
    fill_k<<<eb * 8, 256, 0, stream>>>(srcp, dstp, etp, ea, rowstart3, cursor3,
                                       pay, E, N);

    const unsigned short* Bf2 = Bf + (size_t)96 * 64 * 8;

    // layer 1 (xconv fused into logits)
    xlogits_k<<<nb4, 256, 0, stream>>>(x, wqk + 0, wqk + 384, xbf, nq3, nk3, N);
    edgeex_k<<<eb, 256, 0, stream>>>(pay, nq3, nk3, cc, 0, ex_s, E);
    agg_k<<<nb4, 256, 0, stream>>>(xbf, pay, ex_s, rowstart3, aggbf, N);
    gemm_mfma_k<1><<<mb64, 256, 0, stream>>>(aggbf, Bf, b1, hbf, nullptr, N);

    // layer 2
    logits_k<<<nb4, 256, 0, stream>>>(hbf, wqk + 768, wqk + 1152, nq3, nk3, N);
    edgeex_k<<<eb, 256, 0, stream>>>(pay, nq3, nk3, cc, 1, ex_s, E);
    agg_k<<<nb4, 256, 0, stream>>>(hbf, pay, ex_s, rowstart3, aggbf, N);
    gemm_mfma_k<0><<<mb64, 256, 0, stream>>>(aggbf, Bf2, b2, nullptr, out, N);
}